// Round 9
// baseline (608.513 us; speedup 1.0000x reference)
//
#include <hip/hip_runtime.h>
#include <cstdint>

typedef __attribute__((ext_vector_type(8))) short bf16x8;
typedef __attribute__((ext_vector_type(4))) float f32x4;
typedef __attribute__((address_space(1))) unsigned int ga_u32;
typedef __attribute__((address_space(3))) unsigned int ls_u32;

// ---------- helpers ----------
__device__ __forceinline__ float bf2f(unsigned short u) {
    union { unsigned int i; float f; } v; v.i = ((unsigned int)u) << 16; return v.f;
}
__device__ __forceinline__ float bfhi(unsigned int w) {
    union { unsigned int i; float f; } v; v.i = w & 0xffff0000u; return v.f;
}
__device__ __forceinline__ float bflo(unsigned int w) {
    union { unsigned int i; float f; } v; v.i = w << 16; return v.f;
}
__device__ __forceinline__ unsigned short f2bf(float f) {
    union { float ff; unsigned int i; } v; v.ff = f;
    unsigned int r = (v.i + 0x7fffu + ((v.i >> 16) & 1u)) >> 16;
    return (unsigned short)r;
}
// gate-permuted column -> original column (nc in [0,384))
__device__ __forceinline__ int origcol(int nc) {
    int w = nc / 96, rem = nc % 96, g = rem / 32, cc = rem % 32;
    return g * 128 + w * 32 + cc;
}

// ---------- runtime dtype detection ----------
__global__ void detect_kernel(const unsigned int* __restrict__ x32,
                              const int* __restrict__ ei32,
                              int* __restrict__ flags)
{
    __shared__ int insaneS;
    __shared__ int orS;
    int tid = threadIdx.x;
    if (tid == 0) { insaneS = 0; orS = 0; }
    __syncthreads();
    int insane = 0;
    for (int j = tid; j < 512; j += 256) {
        unsigned int w = x32[j];
        int e = (int)((w >> 7) & 0xFF);
        if (e > 135 || e < 100) insane++;
    }
    int ov = 0;
    for (int j = tid; j < 256; j += 256) ov |= ei32[2 * j + 1];
    atomicAdd(&insaneS, insane);
    atomicOr(&orS, ov);
    __syncthreads();
    if (tid == 0) {
        flags[0] = (insaneS < 64) ? 1 : 0;   // 1 = bf16-packed floats
        flags[1] = (orS == 0) ? 1 : 0;       // 1 = int64 edges
    }
}

// ---------- all-weights conversion (bf16-or-f32 -> f32), one launch ----------
__global__ void convall_kernel(const void* W_in, const void* W_mpnn, const void* W_ih,
                               const void* W_hh, const void* b_ih, const void* b_hh,
                               const void* W_pred, const void* b_pred,
                               float* __restrict__ Winf, float* __restrict__ Wmf,
                               float* __restrict__ Wihf, float* __restrict__ Whhf,
                               float* __restrict__ bihf, float* __restrict__ bhhf,
                               float* __restrict__ Wpf, float* __restrict__ bpf,
                               int steps, const int* __restrict__ flags)
{
    int i = blockIdx.x * 256 + threadIdx.x;
    int bf = flags[0];
    auto get = [&](const void* p, int idx) -> float {
        return bf ? bf2f(((const unsigned short*)p)[idx]) : ((const float*)p)[idx];
    };
    int n0 = 8192, n1 = n0 + steps * 16384, n2 = n1 + 49152, n3 = n2 + 49152;
    int n4 = n3 + 384, n5 = n4 + 384, n6 = n5 + 128, n7 = n6 + 1;
    if      (i < n0) Winf[i]      = get(W_in,   i);
    else if (i < n1) Wmf[i - n0]  = get(W_mpnn, i - n0);
    else if (i < n2) Wihf[i - n1] = get(W_ih,   i - n1);
    else if (i < n3) Whhf[i - n2] = get(W_hh,   i - n2);
    else if (i < n4) bihf[i - n3] = get(b_ih,   i - n3);
    else if (i < n5) bhhf[i - n4] = get(b_hh,   i - n4);
    else if (i < n6) Wpf[i - n5]  = get(W_pred, i - n5);
    else if (i < n7) bpf[i - n6]  = get(b_pred, i - n6);
}

// Wcomb[step][k][j] = sum_t W_mpnn[step][k][t] * W_ih[j][t]   ([steps][128][384])
__global__ void wcomb_kernel(const float* __restrict__ Wm,
                             const float* __restrict__ Wih,
                             float* __restrict__ Wcomb, int steps)
{
    int i = blockIdx.x * 256 + threadIdx.x;
    int total = steps * 49152;
    if (i >= total) return;
    int step = i / 49152;
    int rem = i - step * 49152;
    int k = rem / 384;
    int j = rem - k * 384;
    const float* wm = Wm + ((long)step * 128 + k) * 128;
    const float* wi = Wih + (long)j * 128;
    float s = 0.f;
#pragma unroll 8
    for (int t = 0; t < 128; ++t) s += wm[t] * wi[t];
    Wcomb[i] = s;
}

// ---------- pack weights into MFMA-fragment-ready bf16 layout ----------
__global__ void pack_gates(const float* __restrict__ Wcomb,
                           const float* __restrict__ Whhf,
                           const float* __restrict__ bihf, const float* __restrict__ bhhf,
                           unsigned short* __restrict__ Bci,
                           unsigned short* __restrict__ Bhh,
                           float* __restrict__ bip, float* __restrict__ bhp,
                           int steps)
{
    int i = blockIdx.x * 256 + threadIdx.x;
    int nmat = steps * 49152;
    if (i < nmat) {
        int s = i / 49152, r = i - s * 49152;
        int t = r >> 11, rem = r & 2047;
        int ks = rem >> 9, l = (rem >> 3) & 63, j = rem & 7;
        int k = ks * 32 + (l >> 4) * 8 + j;
        int oc = origcol(t * 16 + (l & 15));
        Bci[i] = f2bf(Wcomb[(long)s * 49152 + k * 384 + oc]);
    } else if (i < nmat + 49152) {
        int r = i - nmat;
        int t = r >> 11, rem = r & 2047;
        int ks = rem >> 9, l = (rem >> 3) & 63, j = rem & 7;
        int k = ks * 32 + (l >> 4) * 8 + j;
        int oc = origcol(t * 16 + (l & 15));
        Bhh[r] = f2bf(Whhf[(long)oc * 128 + k]);
    } else if (i < nmat + 49152 + 768) {
        int b = i - nmat - 49152;
        if (b < 384) bip[b] = bihf[origcol(b)];
        else         bhp[b - 384] = bhhf[origcol(b - 384)];
    }
}

// pack W_in ([128][64] row-major fp32) -> [8 t][2 ks][64][8] bf16
__global__ void pack_in(const float* __restrict__ Winf, unsigned short* __restrict__ Bin)
{
    int r = blockIdx.x * 256 + threadIdx.x;
    if (r >= 8192) return;
    int t = r >> 10, rem = r & 1023;
    int ks = rem >> 9, l = (rem >> 3) & 63, j = rem & 7;
    int k = ks * 32 + (l >> 4) * 8 + j;
    int col = t * 16 + (l & 15);
    Bin[r] = f2bf(Winf[col * 64 + k]);
}

// ---------- input embedding: h = x @ W_in^T (MFMA, raw x w/ runtime dtype) ----------
__global__ __launch_bounds__(256) void gemm_in(const void* __restrict__ xraw,
                        const int* __restrict__ flags,
                        const unsigned short* __restrict__ Bin,
                        unsigned short* __restrict__ hout, int N)
{
    const int w = threadIdx.x >> 6, lane = threadIdx.x & 63;
    const int m = lane & 15, quad = lane >> 4;
    const int rowBase = blockIdx.x * 32;
    const bool abf = flags[0] != 0;
    f32x4 acc[2][2];
#pragma unroll
    for (int rt = 0; rt < 2; ++rt)
#pragma unroll
        for (int ct = 0; ct < 2; ++ct) acc[rt][ct] = (f32x4){0.f, 0.f, 0.f, 0.f};

#pragma unroll
    for (int ks = 0; ks < 2; ++ks) {
        bf16x8 a[2];
#pragma unroll
        for (int rt = 0; rt < 2; ++rt) {
            long row = rowBase + rt * 16 + m;
            if (abf) {
                a[rt] = *(const bf16x8*)(const void*)((const unsigned short*)xraw + row * 64 + ks * 32 + quad * 8);
            } else {
                const float* xp = (const float*)xraw + row * 64 + ks * 32 + quad * 8;
                float4 f0 = *(const float4*)xp;
                float4 f1 = *(const float4*)(xp + 4);
                bf16x8 t;
                t[0] = (short)f2bf(f0.x); t[1] = (short)f2bf(f0.y);
                t[2] = (short)f2bf(f0.z); t[3] = (short)f2bf(f0.w);
                t[4] = (short)f2bf(f1.x); t[5] = (short)f2bf(f1.y);
                t[6] = (short)f2bf(f1.z); t[7] = (short)f2bf(f1.w);
                a[rt] = t;
            }
        }
#pragma unroll
        for (int ct = 0; ct < 2; ++ct) {
            int t = w * 2 + ct;
            bf16x8 b = *(const bf16x8*)(const void*)(Bin + ((t * 2 + ks) * 64 + lane) * 8);
#pragma unroll
            for (int rt = 0; rt < 2; ++rt)
                acc[rt][ct] = __builtin_amdgcn_mfma_f32_16x16x32_bf16(a[rt], b, acc[rt][ct], 0, 0, 0);
        }
    }
#pragma unroll
    for (int rt = 0; rt < 2; ++rt)
#pragma unroll
        for (int ct = 0; ct < 2; ++ct)
#pragma unroll
            for (int reg = 0; reg < 4; ++reg) {
                int row = rowBase + rt * 16 + quad * 4 + reg;
                int col = w * 32 + ct * 16 + m;
                if (row < N) hout[(long)row * 128 + col] = f2bf(acc[rt][ct][reg]);
            }
}

// ---------- MPNN+GRU step: PERSISTENT blocks, B-resident, 64-row iterations ----------
// 256 blocks (1/CU) x 512 thr. B fragments resident (loaded once). Grid-stride over
// 64-row tiles (2 x 32-row subtiles per iteration): halves barrier/wait events vs
// 32-row tiles. Double-buffered LDS (2 x 32KB). Counted s_waitcnt vmcnt(20):
// steady-state outstanding at the wait = 16 epilogue stores + 4 next-tile loads,
// so waiting to <=20 retires exactly the current tile's 4 loads WITHOUT draining
// stores (the round-8 vmcnt(2) store-drain exposure). One-time vmcnt(0) pre-loop
// covers the first tile + B/bias loads.
__global__ __launch_bounds__(512, 2) void step_kernel(
    const unsigned short* __restrict__ hin,
    const unsigned short* __restrict__ aggb,
    const unsigned short* __restrict__ Bci,
    const unsigned short* __restrict__ Bhh,
    const float* __restrict__ bip, const float* __restrict__ bhp,
    unsigned short* __restrict__ hout, int N, int ntiles)
{
    __shared__ unsigned short lds[32768];  // 2 bufs x (agg[2x4096] | h[2x4096]) shorts
    const int tid = threadIdx.x;
    const int w = tid >> 6, lane = tid & 63;
    const int m = lane & 15, quad = lane >> 4;
    const int cg = w >> 1, half = w & 1;
    const int col = cg * 32 + half * 16 + m;
    const int grid = gridDim.x;

    // ---- resident B fragments (loaded once) ----
    bf16x8 bI[4][3], bH[4][3];
#pragma unroll
    for (int ks = 0; ks < 4; ++ks)
#pragma unroll
        for (int g = 0; g < 3; ++g) {
            int t = cg * 6 + g * 2 + half;
            bI[ks][g] = *(const bf16x8*)(const void*)(Bci + (((long)t * 4 + ks) * 64 + lane) * 8);
            bH[ks][g] = *(const bf16x8*)(const void*)(Bhh + (((long)t * 4 + ks) * 64 + lane) * 8);
        }
    // ---- resident biases ----
    float bi0[3], bh0[3];
#pragma unroll
    for (int g = 0; g < 3; ++g) {
        int nc = (cg * 6 + g * 2 + half) * 16 + m;
        bi0[g] = bip[nc]; bh0[g] = bhp[nc];
    }

    // staging geometry (constant per thread); each issue covers one 32-row region
    const int lrow = w * 4 + (lane >> 4);           // region row of this lane's 16B
    const int schunk = (lane & 15) ^ (lrow & 7);    // XOR-swizzled source chunk

    auto stage = [&](long t, int buf) {
        const unsigned short* ga0 = aggb + (t * 64 + lrow) * 128 + schunk * 8;
        const unsigned short* ga1 = aggb + (t * 64 + 32 + lrow) * 128 + schunk * 8;
        const unsigned short* gh0 = hin  + (t * 64 + lrow) * 128 + schunk * 8;
        const unsigned short* gh1 = hin  + (t * 64 + 32 + lrow) * 128 + schunk * 8;
        unsigned short* base = lds + buf * 16384;
        __builtin_amdgcn_global_load_lds((const ga_u32*)ga0, (ls_u32*)(base + w * 512), 16, 0, 0);
        __builtin_amdgcn_global_load_lds((const ga_u32*)ga1, (ls_u32*)(base + 4096 + w * 512), 16, 0, 0);
        __builtin_amdgcn_global_load_lds((const ga_u32*)gh0, (ls_u32*)(base + 8192 + w * 512), 16, 0, 0);
        __builtin_amdgcn_global_load_lds((const ga_u32*)gh1, (ls_u32*)(base + 12288 + w * 512), 16, 0, 0);
    };

    long tile = blockIdx.x;
    int cur = 0;
    if (tile < ntiles) stage(tile, 0);
    asm volatile("s_waitcnt vmcnt(0)" ::: "memory");   // one-time: B, biases, tile0

    for (; tile < ntiles; tile += grid) {
        long nxt = tile + grid;
        if (nxt < ntiles) {
            stage(nxt, cur ^ 1);
            // steady state: outstanding = [tile's 4 (done by now or waited here)]
            // + 16 stores + 4 new loads; <=20 retires exactly the oldest 4 loads.
            asm volatile("s_waitcnt vmcnt(20)" ::: "memory");
        } else {
            asm volatile("s_waitcnt vmcnt(0)" ::: "memory");
        }
        __builtin_amdgcn_s_barrier();

#pragma unroll
        for (int sub = 0; sub < 2; ++sub) {
            const unsigned short* abuf = lds + cur * 16384 + sub * 4096;
            const unsigned short* hbuf = lds + cur * 16384 + 8192 + sub * 4096;

            // accumulators (bias-initialized)
            f32x4 gi[2][3], gh[2][3];
#pragma unroll
            for (int g = 0; g < 3; ++g)
#pragma unroll
                for (int rt = 0; rt < 2; ++rt) {
                    gi[rt][g] = (f32x4){bi0[g], bi0[g], bi0[g], bi0[g]};
                    gh[rt][g] = (f32x4){bh0[g], bh0[g], bh0[g], bh0[g]};
                }

#pragma unroll
            for (int ks = 0; ks < 4; ++ks) {
                bf16x8 aA[2], hA[2];
#pragma unroll
                for (int rt = 0; rt < 2; ++rt) {
                    int r = rt * 16 + m;
                    int ch = (ks * 4 + quad) ^ (r & 7);
                    aA[rt] = *(const bf16x8*)(const void*)(abuf + r * 128 + ch * 8);
                    hA[rt] = *(const bf16x8*)(const void*)(hbuf + r * 128 + ch * 8);
                }
#pragma unroll
                for (int g = 0; g < 3; ++g)
#pragma unroll
                    for (int rt = 0; rt < 2; ++rt) {
                        gi[rt][g] = __builtin_amdgcn_mfma_f32_16x16x32_bf16(aA[rt], bI[ks][g], gi[rt][g], 0, 0, 0);
                        gh[rt][g] = __builtin_amdgcn_mfma_f32_16x16x32_bf16(hA[rt], bH[ks][g], gh[rt][g], 0, 0, 0);
                    }
            }

            // GRU epilogue: g=0 -> r, g=1 -> z, g=2 -> n; hold re-read from h LDS
            long rowBase = tile * 64 + sub * 32;
#pragma unroll
            for (int rt = 0; rt < 2; ++rt)
#pragma unroll
                for (int reg = 0; reg < 4; ++reg) {
                    long row = rowBase + rt * 16 + quad * 4 + reg;
                    if (row < N) {
                        int r2 = rt * 16 + quad * 4 + reg;
                        int hidx = r2 * 128 + ((((col >> 3) ^ (r2 & 7)) << 3) + (col & 7));
                        float R  = __builtin_amdgcn_rcpf(1.f + __expf(-(gi[rt][0][reg] + gh[rt][0][reg])));
                        float Z  = __builtin_amdgcn_rcpf(1.f + __expf(-(gi[rt][1][reg] + gh[rt][1][reg])));
                        float u  = gi[rt][2][reg] + R * gh[rt][2][reg];
                        float e2 = __expf(-2.f * fabsf(u));
                        float Nn = copysignf((1.f - e2) * __builtin_amdgcn_rcpf(1.f + e2), u);
                        float hold = bf2f(hbuf[hidx]);
                        hout[row * 128 + col] = f2bf((1.f - Z) * Nn + Z * hold);
                    }
                }
        }

        __builtin_amdgcn_s_barrier();   // all waves done reading cur before restage
        cur ^= 1;
    }
}

// ---------- CSR build pass 1: radix partition into coarse buckets ----------
__global__ __launch_bounds__(256) void part1_kernel(
    const int* __restrict__ ei, int E, const int* __restrict__ flags,
    int* __restrict__ gcnt, uint2* __restrict__ pair2,
    int nb, int cshift, int ccap, int chunk)
{
    __shared__ int cnt[256];
    __shared__ int base_s[256];
    const int tid = threadIdx.x;
    if (tid < nb) cnt[tid] = 0;
    __syncthreads();
    const bool i64 = flags[1] != 0;
    const long long* e64 = (const long long*)ei;
    int lo = blockIdx.x * chunk;
    int hi = lo + chunk; if (hi > E) hi = E;
    for (int i = lo + tid; i < hi; i += 256) {
        int d = i64 ? (int)e64[(long)E + i] : ei[(long)E + i];
        atomicAdd(&cnt[d >> cshift], 1);
    }
    __syncthreads();
    if (tid < nb) {
        int c = cnt[tid];
        base_s[tid] = (c > 0) ? atomicAdd(&gcnt[tid], c) : 0;
        cnt[tid] = 0;
    }
    __syncthreads();
    for (int i = lo + tid; i < hi; i += 256) {
        int s, d;
        if (i64) { s = (int)e64[i]; d = (int)e64[(long)E + i]; }
        else     { s = ei[i];       d = ei[(long)E + i]; }
        int c = d >> cshift;
        int p = base_s[c] + atomicAdd(&cnt[c], 1);
        if (p < ccap) { uint2 pr; pr.x = (unsigned)s; pr.y = (unsigned)d; pair2[(long)c * ccap + p] = pr; }
    }
}

// exclusive scan of coarse-bucket counts (nb <= 256, single block)
__global__ void scanco_kernel(const int* __restrict__ gcnt, int* __restrict__ cbase,
                              int nb, int ccap)
{
    __shared__ int wsum[4];
    int tid = threadIdx.x, lane = tid & 63, wv = tid >> 6;
    int x = (tid < nb) ? gcnt[tid] : 0;
    if (x > ccap) x = ccap;
    int inc = x;
#pragma unroll
    for (int d = 1; d < 64; d <<= 1) { int u = __shfl_up(inc, d); if (lane >= d) inc += u; }
    if (lane == 63) wsum[wv] = inc;
    __syncthreads();
    if (tid == 0) { int s = 0; for (int q = 0; q < 4; ++q) { int t = wsum[q]; wsum[q] = s; s += t; } }
    __syncthreads();
    int excl = wsum[wv] + inc - x;
    if (tid < nb) cbase[tid] = excl;
    if (tid == nb - 1) cbase[nb] = excl + x;
}

// ---------- CSR build pass 2: per-coarse-bucket counting sort -> offs + csr ----------
__global__ __launch_bounds__(256) void part2_kernel(
    const uint2* __restrict__ pair2, const int* __restrict__ gcnt,
    const int* __restrict__ cbase,
    int* __restrict__ offs, int* __restrict__ csr,
    int N, int nb, int cshift, int ccap)
{
    __shared__ int lb[2048];
    __shared__ int wsum[4];
    const int b = blockIdx.x, tid = threadIdx.x;
    const int span = 1 << cshift;
    const int n0 = b << cshift;
    int count = gcnt[b]; if (count > ccap) count = ccap;
    for (int k = tid; k < span; k += 256) lb[k] = 0;
    __syncthreads();
    const uint2* pp = pair2 + (long)b * ccap;
    for (int i = tid; i < count; i += 256)
        atomicAdd(&lb[(int)pp[i].y - n0], 1);
    __syncthreads();
    int npe = span >> 8; if (npe < 1) npe = 1;
    int myb = tid * npe;
    int vals[8];
    int sum = 0;
    for (int k = 0; k < npe; ++k) { vals[k] = lb[myb + k]; sum += vals[k]; }
    int lane = tid & 63, wv = tid >> 6;
    int inc = sum;
#pragma unroll
    for (int d = 1; d < 64; d <<= 1) { int u = __shfl_up(inc, d); if (lane >= d) inc += u; }
    if (lane == 63) wsum[wv] = inc;
    __syncthreads();
    if (tid == 0) { int s = 0; for (int q = 0; q < 4; ++q) { int t = wsum[q]; wsum[q] = s; s += t; } }
    __syncthreads();
    int run = wsum[wv] + inc - sum;
    __syncthreads();
    for (int k = 0; k < npe; ++k) { lb[myb + k] = run; run += vals[k]; }
    __syncthreads();
    int gb = cbase[b];
    int nn = N - n0; if (nn > span) nn = span;
    for (int g = tid; g < nn; g += 256) offs[n0 + g] = gb + lb[g];
    if (b == nb - 1 && tid == 0) offs[N] = cbase[nb];
    __syncthreads();
    for (int i = tid; i < count; i += 256) {
        uint2 pr = pp[i];
        int p = gb + atomicAdd(&lb[(int)pr.y - n0], 1);
        csr[p] = (int)pr.x;
    }
}

// ---------- aggregation: persistent waves, contiguous node chunks ----------
// (pinned at the measured gather ceiling ~3.45 TB/s; do not touch)
__global__ __launch_bounds__(256) void aggregate(const unsigned short* __restrict__ hb,
                          const int* __restrict__ off,
                          const int* __restrict__ csr,
                          unsigned short* __restrict__ aggb, int n)
{
    int wv = threadIdx.x >> 6, lane = threadIdx.x & 63;
    int slot = lane >> 4;
    int c16 = lane & 15;
    int nw = gridDim.x * 4;                 // total waves
    int wid = blockIdx.x * 4 + wv;
    int chunk = (n + nw - 1) / nw;
    int lo = wid * chunk;
    int hi = lo + chunk; if (hi > n) hi = n;

    for (int node = lo; node < hi; ++node) {
        int s0 = off[node], s1 = off[node + 1];
        float a0 = 0.f, a1 = 0.f, a2 = 0.f, a3 = 0.f, a4 = 0.f, a5 = 0.f, a6 = 0.f, a7 = 0.f;
        if (s1 > s0) {
            int last = s1 - 1;
            for (int j = s0 + slot; j < s1; j += 16) {
                uint4 vv[4];
                float wt[4];
#pragma unroll
                for (int t = 0; t < 4; ++t) {
                    int jj = j + 4 * t;
                    int idx = csr[jj <= last ? jj : last];
                    vv[t] = *(const uint4*)(const void*)(hb + (long)idx * 128 + c16 * 8);
                    wt[t] = (jj <= last) ? 1.f : 0.f;
                }
#pragma unroll
                for (int t = 0; t < 4; ++t) {
                    a0 = fmaf(bflo(vv[t].x), wt[t], a0);
                    a1 = fmaf(bfhi(vv[t].x), wt[t], a1);
                    a2 = fmaf(bflo(vv[t].y), wt[t], a2);
                    a3 = fmaf(bfhi(vv[t].y), wt[t], a3);
                    a4 = fmaf(bflo(vv[t].z), wt[t], a4);
                    a5 = fmaf(bfhi(vv[t].z), wt[t], a5);
                    a6 = fmaf(bflo(vv[t].w), wt[t], a6);
                    a7 = fmaf(bfhi(vv[t].w), wt[t], a7);
                }
            }
        }
        a0 += __shfl_xor(a0, 16); a1 += __shfl_xor(a1, 16);
        a2 += __shfl_xor(a2, 16); a3 += __shfl_xor(a3, 16);
        a4 += __shfl_xor(a4, 16); a5 += __shfl_xor(a5, 16);
        a6 += __shfl_xor(a6, 16); a7 += __shfl_xor(a7, 16);
        a0 += __shfl_xor(a0, 32); a1 += __shfl_xor(a1, 32);
        a2 += __shfl_xor(a2, 32); a3 += __shfl_xor(a3, 32);
        a4 += __shfl_xor(a4, 32); a5 += __shfl_xor(a5, 32);
        a6 += __shfl_xor(a6, 32); a7 += __shfl_xor(a7, 32);
        if (slot == 0) {
            uint4 o;
            o.x = ((unsigned int)f2bf(a1) << 16) | f2bf(a0);
            o.y = ((unsigned int)f2bf(a3) << 16) | f2bf(a2);
            o.z = ((unsigned int)f2bf(a5) << 16) | f2bf(a4);
            o.w = ((unsigned int)f2bf(a7) << 16) | f2bf(a6);
            *(uint4*)(void*)(aggb + (long)node * 128 + c16 * 8) = o;
        }
    }
}

// ---------- readout ----------
__global__ void colsum(const unsigned short* __restrict__ hb, float* __restrict__ acc, int n) {
    int c = threadIdx.x & 127;
    int sub = threadIdx.x >> 7;
    float local = 0.f;
    for (long r = blockIdx.x * 2 + sub; r < n; r += (long)gridDim.x * 2) {
        float v = bf2f(hb[r * 128 + c]);
        local += (v >= 0.f) ? v : 0.01f * v;
    }
    atomicAdd(&acc[c], local);
}

__global__ void finalize(const float* __restrict__ acc,
                         const float* __restrict__ W_pred_f,
                         const float* __restrict__ b_pred_f,
                         unsigned int* __restrict__ out, float invN)
{
    __shared__ float ws2[2];
    int t = threadIdx.x;  // 128 threads
    float v = acc[t] * invN * W_pred_f[t];
#pragma unroll
    for (int d = 32; d >= 1; d >>= 1) v += __shfl_down(v, d);
    if ((t & 63) == 0) ws2[t >> 6] = v;
    __syncthreads();
    if (t == 0) {
        float r = ws2[0] + ws2[1] + b_pred_f[0];
        unsigned int bf = (unsigned int)f2bf(r);
        out[0] = (bf << 16) | bf;   // dual-dtype store
    }
}

// ---------- host ----------
extern "C" void kernel_launch(void* const* d_in, const int* in_sizes, int n_in,
                              void* d_out, int out_size, void* d_ws, size_t ws_size,
                              hipStream_t stream)
{
    const void* x      = d_in[0];
    const int*  ei     = (const int*)d_in[1];
    const void* W_in   = d_in[2];
    const void* W_mpnn = d_in[3];
    const void* W_ih   = d_in[4];
    const void* W_hh   = d_in[5];
    const void* b_ih   = d_in[6];
    const void* b_hh   = d_in[7];
    const void* W_pred = d_in[8];
    const void* b_pred = d_in[9];

    const int N = in_sizes[0] / 64;              // 100000
    const int E = in_sizes[1] / 2;               // 1600000
    const int STEPS = in_sizes[3] / (128 * 128); // 4

    int cshift = 9;
    while ((((N + (1 << cshift) - 1) >> cshift)) > 256 && cshift < 11) cshift++;
    const int NCO = (N + (1 << cshift) - 1) >> cshift;
    const int ccap = (((E / NCO) * 3 / 2 + 1024) + 255) & ~255;
    const int chunk = (E + 255) / 256;

    size_t woff = 0;
    auto carve = [&](size_t bytes) -> void* {
        void* p = (char*)d_ws + woff;
        woff = (woff + bytes + 255) & ~(size_t)255;
        return p;
    };
    int*   flags = (int*)carve(2 * 4);
    float* Winf  = (float*)carve(8192 * 4);
    float* Wmf   = (float*)carve((size_t)STEPS * 16384 * 4);
    float* Wihf  = (float*)carve(49152 * 4);
    float* Whhf  = (float*)carve(49152 * 4);
    float* bihf  = (float*)carve(384 * 4);
    float* bhhf  = (float*)carve(384 * 4);
    float* Wpf   = (float*)carve(128 * 4);
    float* bpf   = (float*)carve(4);
    float* Wcomb = (float*)carve((size_t)STEPS * 49152 * 4);
    unsigned short* Bci = (unsigned short*)carve((size_t)STEPS * 49152 * 2);
    unsigned short* Bhh = (unsigned short*)carve(49152 * 2);
    unsigned short* Bin = (unsigned short*)carve(8192 * 2);
    float* bip   = (float*)carve(384 * 4);
    float* bhp   = (float*)carve(384 * 4);
    unsigned short* hA   = (unsigned short*)carve(((size_t)N * 128 + 16384) * 2);
    unsigned short* hB   = (unsigned short*)carve(((size_t)N * 128 + 16384) * 2);
    unsigned short* aggb = (unsigned short*)carve(((size_t)N * 128 + 16384) * 2);
    int*   gcnt  = (int*)carve(256 * 4);
    int*   cbase = (int*)carve(257 * 4);
    int*   offs  = (int*)carve((size_t)(N + 1) * 4);
    int*   csr   = (int*)carve((size_t)E * 4 + 256);
    uint2* pair2 = (uint2*)carve((size_t)NCO * ccap * 8);
    float* accb  = (float*)carve(128 * 4);

    hipMemsetAsync(gcnt, 0, 256 * 4, stream);
    hipMemsetAsync(accb, 0, 128 * 4, stream);

    detect_kernel<<<1, 256, 0, stream>>>((const unsigned int*)x, ei, flags);

    {
        int total = 8192 + STEPS * 16384 + 2 * 49152 + 768 + 129;
        convall_kernel<<<(total + 255) / 256, 256, 0, stream>>>(
            W_in, W_mpnn, W_ih, W_hh, b_ih, b_hh, W_pred, b_pred,
            Winf, Wmf, Wihf, Whhf, bihf, bhhf, Wpf, bpf, STEPS, flags);
    }

    wcomb_kernel<<<(STEPS * 49152 + 255) / 256, 256, 0, stream>>>(Wmf, Wihf, Wcomb, STEPS);
    {
        int total = (STEPS + 1) * 49152 + 768;
        pack_gates<<<(total + 255) / 256, 256, 0, stream>>>(Wcomb, Whhf, bihf, bhhf,
                                                            Bci, Bhh, bip, bhp, STEPS);
    }
    pack_in<<<32, 256, 0, stream>>>(Winf, Bin);

    // h0 = x @ W_in^T (reads raw x, runtime dtype)
    gemm_in<<<(N + 31) / 32, 256, 0, stream>>>(x, flags, Bin, hA, N);

    // CSR build: radix partition -> coarse scan -> per-bucket counting sort
    part1_kernel<<<256, 256, 0, stream>>>(ei, E, flags, gcnt, pair2, NCO, cshift, ccap, chunk);
    scanco_kernel<<<1, 256, 0, stream>>>(gcnt, cbase, NCO, ccap);
    part2_kernel<<<NCO, 256, 0, stream>>>(pair2, gcnt, cbase, offs, csr, N, NCO, cshift, ccap);

    int aggBlocks = (N + 3) / 4; if (aggBlocks > 2048) aggBlocks = 2048;
    const int ntiles = (N + 63) / 64;
    int stepBlocks = ntiles < 256 ? ntiles : 256;
    unsigned short* hcur = hA;
    unsigned short* hnxt = hB;
    for (int step = 0; step < STEPS; ++step) {
        aggregate<<<aggBlocks, 256, 0, stream>>>(hcur, offs, csr, aggb, N);
        step_kernel<<<stepBlocks, 512, 0, stream>>>(
            hcur, aggb, Bci + (size_t)step * 49152, Bhh, bip, bhp, hnxt, N, ntiles);
        unsigned short* t = hcur; hcur = hnxt; hnxt = t;
    }

    colsum<<<512, 256, 0, stream>>>(hcur, accb, N);
    finalize<<<1, 128, 0, stream>>>(accb, Wpf, bpf, (unsigned int*)d_out, 1.f / (float)N);
}

// Round 10
// 602.285 us; speedup vs baseline: 1.0103x; 1.0103x over previous
//
#include <hip/hip_runtime.h>
#include <cstdint>

typedef __attribute__((ext_vector_type(8))) short bf16x8;
typedef __attribute__((ext_vector_type(4))) float f32x4;
typedef __attribute__((address_space(1))) unsigned int ga_u32;
typedef __attribute__((address_space(3))) unsigned int ls_u32;

// ---------- helpers ----------
__device__ __forceinline__ float bf2f(unsigned short u) {
    union { unsigned int i; float f; } v; v.i = ((unsigned int)u) << 16; return v.f;
}
__device__ __forceinline__ float bfhi(unsigned int w) {
    union { unsigned int i; float f; } v; v.i = w & 0xffff0000u; return v.f;
}
__device__ __forceinline__ float bflo(unsigned int w) {
    union { unsigned int i; float f; } v; v.i = w << 16; return v.f;
}
__device__ __forceinline__ unsigned short f2bf(float f) {
    union { float ff; unsigned int i; } v; v.ff = f;
    unsigned int r = (v.i + 0x7fffu + ((v.i >> 16) & 1u)) >> 16;
    return (unsigned short)r;
}
// gate-permuted column -> original column (nc in [0,384))
__device__ __forceinline__ int origcol(int nc) {
    int w = nc / 96, rem = nc % 96, g = rem / 32, cc = rem % 32;
    return g * 128 + w * 32 + cc;
}

// ---------- FUSED prep: detect + convert + wcomb-dot + pack (one launch) ----------
// Replaces detect/convall/wcomb/pack_gates/pack_in. Each block redundantly
// computes the dtype flag (3KB read, L2-broadcast); block 0 publishes flags.
// Bci outputs compute the Wcomb dot product INLINE from raw weights (no
// intermediate fp32 buffers at all).
__global__ __launch_bounds__(256) void prep_kernel(
    const unsigned int* __restrict__ x32, const int* __restrict__ ei32,
    const void* W_in, const void* W_mpnn, const void* W_ih, const void* W_hh,
    const void* b_ih, const void* b_hh, const void* W_pred, const void* b_pred,
    unsigned short* __restrict__ Bci, unsigned short* __restrict__ Bhh,
    float* __restrict__ bip, float* __restrict__ bhp,
    unsigned short* __restrict__ Bin,
    float* __restrict__ Wpf, float* __restrict__ bpf,
    int* __restrict__ flags, int steps)
{
    __shared__ int insaneS, orS;
    const int tid = threadIdx.x;
    if (tid == 0) { insaneS = 0; orS = 0; }
    __syncthreads();
    {
        int insane = 0;
        for (int j = tid; j < 512; j += 256) {
            unsigned int w = x32[j];
            int e = (int)((w >> 7) & 0xFF);
            if (e > 135 || e < 100) insane++;
        }
        int ov = 0;
        for (int j = tid; j < 256; j += 256) ov |= ei32[2 * j + 1];
        atomicAdd(&insaneS, insane);
        atomicOr(&orS, ov);
    }
    __syncthreads();
    const bool bf = insaneS < 64;
    if (blockIdx.x == 0 && tid == 0) {
        flags[0] = bf ? 1 : 0;
        flags[1] = (orS == 0) ? 1 : 0;
    }

    auto cvt = [&](const void* p, long idx) -> float {
        return bf ? bf2f(((const unsigned short*)p)[idx]) : ((const float*)p)[idx];
    };

    const long n1 = (long)steps * 49152;       // Bci
    const long n2 = n1 + 49152;                // Bhh
    const long n3 = n2 + 768;                  // biases
    const long n4 = n3 + 8192;                 // Bin
    const long n5 = n4 + 128;                  // Wpf
    long i = (long)blockIdx.x * 256 + tid;

    if (i < n1) {
        int st = (int)(i / 49152), r = (int)(i - (long)st * 49152);
        int t = r >> 11, rem = r & 2047;
        int ks = rem >> 9, l = (rem >> 3) & 63, j = rem & 7;
        int k = ks * 32 + (l >> 4) * 8 + j;
        int oc = origcol(t * 16 + (l & 15));
        float s = 0.f;
        if (bf) {
            const unsigned short* wm = (const unsigned short*)W_mpnn + ((long)st * 128 + k) * 128;
            const unsigned short* wi = (const unsigned short*)W_ih + (long)oc * 128;
#pragma unroll 4
            for (int tt = 0; tt < 128; tt += 8) {
                uint4 a = *(const uint4*)(const void*)(wm + tt);
                uint4 b = *(const uint4*)(const void*)(wi + tt);
                s += bflo(a.x) * bflo(b.x) + bfhi(a.x) * bfhi(b.x);
                s += bflo(a.y) * bflo(b.y) + bfhi(a.y) * bfhi(b.y);
                s += bflo(a.z) * bflo(b.z) + bfhi(a.z) * bfhi(b.z);
                s += bflo(a.w) * bflo(b.w) + bfhi(a.w) * bfhi(b.w);
            }
        } else {
            const float* wm = (const float*)W_mpnn + ((long)st * 128 + k) * 128;
            const float* wi = (const float*)W_ih + (long)oc * 128;
#pragma unroll 4
            for (int tt = 0; tt < 128; tt += 4) {
                float4 a = *(const float4*)(wm + tt);
                float4 b = *(const float4*)(wi + tt);
                s += a.x * b.x + a.y * b.y + a.z * b.z + a.w * b.w;
            }
        }
        Bci[i] = f2bf(s);
    } else if (i < n2) {
        int r = (int)(i - n1);
        int t = r >> 11, rem = r & 2047;
        int ks = rem >> 9, l = (rem >> 3) & 63, j = rem & 7;
        int k = ks * 32 + (l >> 4) * 8 + j;
        int oc = origcol(t * 16 + (l & 15));
        Bhh[r] = f2bf(cvt(W_hh, (long)oc * 128 + k));
    } else if (i < n3) {
        int b = (int)(i - n2);
        if (b < 384) bip[b] = cvt(b_ih, origcol(b));
        else         bhp[b - 384] = cvt(b_hh, origcol(b - 384));
    } else if (i < n4) {
        int r = (int)(i - n3);
        int t = r >> 10, rem = r & 1023;
        int ks = rem >> 9, l = (rem >> 3) & 63, j = rem & 7;
        int k = ks * 32 + (l >> 4) * 8 + j;
        int col = t * 16 + (l & 15);
        Bin[r] = f2bf(cvt(W_in, col * 64 + k));
    } else if (i < n5) {
        int idx = (int)(i - n4);
        Wpf[idx] = cvt(W_pred, idx);
    } else if (i == n5) {
        bpf[0] = cvt(b_pred, 0);
    }
}

// ---------- input embedding: h = x @ W_in^T (MFMA, raw x w/ runtime dtype) ----------
__global__ __launch_bounds__(256) void gemm_in(const void* __restrict__ xraw,
                        const int* __restrict__ flags,
                        const unsigned short* __restrict__ Bin,
                        unsigned short* __restrict__ hout, int N)
{
    const int w = threadIdx.x >> 6, lane = threadIdx.x & 63;
    const int m = lane & 15, quad = lane >> 4;
    const int rowBase = blockIdx.x * 32;
    const bool abf = flags[0] != 0;
    f32x4 acc[2][2];
#pragma unroll
    for (int rt = 0; rt < 2; ++rt)
#pragma unroll
        for (int ct = 0; ct < 2; ++ct) acc[rt][ct] = (f32x4){0.f, 0.f, 0.f, 0.f};

#pragma unroll
    for (int ks = 0; ks < 2; ++ks) {
        bf16x8 a[2];
#pragma unroll
        for (int rt = 0; rt < 2; ++rt) {
            long row = rowBase + rt * 16 + m;
            if (abf) {
                a[rt] = *(const bf16x8*)(const void*)((const unsigned short*)xraw + row * 64 + ks * 32 + quad * 8);
            } else {
                const float* xp = (const float*)xraw + row * 64 + ks * 32 + quad * 8;
                float4 f0 = *(const float4*)xp;
                float4 f1 = *(const float4*)(xp + 4);
                bf16x8 t;
                t[0] = (short)f2bf(f0.x); t[1] = (short)f2bf(f0.y);
                t[2] = (short)f2bf(f0.z); t[3] = (short)f2bf(f0.w);
                t[4] = (short)f2bf(f1.x); t[5] = (short)f2bf(f1.y);
                t[6] = (short)f2bf(f1.z); t[7] = (short)f2bf(f1.w);
                a[rt] = t;
            }
        }
#pragma unroll
        for (int ct = 0; ct < 2; ++ct) {
            int t = w * 2 + ct;
            bf16x8 b = *(const bf16x8*)(const void*)(Bin + ((t * 2 + ks) * 64 + lane) * 8);
#pragma unroll
            for (int rt = 0; rt < 2; ++rt)
                acc[rt][ct] = __builtin_amdgcn_mfma_f32_16x16x32_bf16(a[rt], b, acc[rt][ct], 0, 0, 0);
        }
    }
#pragma unroll
    for (int rt = 0; rt < 2; ++rt)
#pragma unroll
        for (int ct = 0; ct < 2; ++ct)
#pragma unroll
            for (int reg = 0; reg < 4; ++reg) {
                int row = rowBase + rt * 16 + quad * 4 + reg;
                int col = w * 32 + ct * 16 + m;
                if (row < N) hout[(long)row * 128 + col] = f2bf(acc[rt][ct][reg]);
            }
}

// ---------- MPNN+GRU step: PERSISTENT blocks, B resident (round-8 best) ----------
__global__ __launch_bounds__(512, 2) void step_kernel(
    const unsigned short* __restrict__ hin,
    const unsigned short* __restrict__ aggb,
    const unsigned short* __restrict__ Bci,
    const unsigned short* __restrict__ Bhh,
    const float* __restrict__ bip, const float* __restrict__ bhp,
    unsigned short* __restrict__ hout, int N, int ntiles)
{
    __shared__ unsigned short lds[16384];  // 2 bufs x (agg[4096] | h[4096]) shorts
    const int tid = threadIdx.x;
    const int w = tid >> 6, lane = tid & 63;
    const int m = lane & 15, quad = lane >> 4;
    const int cg = w >> 1, half = w & 1;
    const int col = cg * 32 + half * 16 + m;
    const int grid = gridDim.x;

    // ---- resident B fragments (loaded once) ----
    bf16x8 bI[4][3], bH[4][3];
#pragma unroll
    for (int ks = 0; ks < 4; ++ks)
#pragma unroll
        for (int g = 0; g < 3; ++g) {
            int t = cg * 6 + g * 2 + half;
            bI[ks][g] = *(const bf16x8*)(const void*)(Bci + (((long)t * 4 + ks) * 64 + lane) * 8);
            bH[ks][g] = *(const bf16x8*)(const void*)(Bhh + (((long)t * 4 + ks) * 64 + lane) * 8);
        }
    // ---- resident biases ----
    float bi0[3], bh0[3];
#pragma unroll
    for (int g = 0; g < 3; ++g) {
        int nc = (cg * 6 + g * 2 + half) * 16 + m;
        bi0[g] = bip[nc]; bh0[g] = bhp[nc];
    }

    // staging geometry (constant per thread)
    const int lrow = w * 4 + (lane >> 4);           // tile row of this lane's 16B
    const int schunk = (lane & 15) ^ (lrow & 7);    // XOR-swizzled source chunk

    long tile = blockIdx.x;
    int cur = 0;
    if (tile < ntiles) {
        const unsigned short* gap = aggb + (tile * 32 + lrow) * 128 + schunk * 8;
        const unsigned short* ghp = hin  + (tile * 32 + lrow) * 128 + schunk * 8;
        __builtin_amdgcn_global_load_lds((const ga_u32*)gap, (ls_u32*)(lds + w * 512), 16, 0, 0);
        __builtin_amdgcn_global_load_lds((const ga_u32*)ghp, (ls_u32*)(lds + 4096 + w * 512), 16, 0, 0);
    }

    for (; tile < ntiles; tile += grid) {
        long nxt = tile + grid;
        bool hasNext = nxt < ntiles;
        if (hasNext) {
            int nb = cur ^ 1;
            const unsigned short* gap = aggb + (nxt * 32 + lrow) * 128 + schunk * 8;
            const unsigned short* ghp = hin  + (nxt * 32 + lrow) * 128 + schunk * 8;
            __builtin_amdgcn_global_load_lds((const ga_u32*)gap, (ls_u32*)(lds + nb * 8192 + w * 512), 16, 0, 0);
            __builtin_amdgcn_global_load_lds((const ga_u32*)ghp, (ls_u32*)(lds + nb * 8192 + 4096 + w * 512), 16, 0, 0);
            asm volatile("s_waitcnt vmcnt(2)" ::: "memory");
        } else {
            asm volatile("s_waitcnt vmcnt(0)" ::: "memory");
        }
        __builtin_amdgcn_s_barrier();

        const unsigned short* abuf = lds + cur * 8192;
        const unsigned short* hbuf = lds + cur * 8192 + 4096;

        // accumulators (bias-initialized)
        f32x4 gi[2][3], gh[2][3];
#pragma unroll
        for (int g = 0; g < 3; ++g)
#pragma unroll
            for (int rt = 0; rt < 2; ++rt) {
                gi[rt][g] = (f32x4){bi0[g], bi0[g], bi0[g], bi0[g]};
                gh[rt][g] = (f32x4){bh0[g], bh0[g], bh0[g], bh0[g]};
            }

#pragma unroll
        for (int ks = 0; ks < 4; ++ks) {
            bf16x8 aA[2], hA[2];
#pragma unroll
            for (int rt = 0; rt < 2; ++rt) {
                int r = rt * 16 + m;
                int ch = (ks * 4 + quad) ^ (r & 7);
                aA[rt] = *(const bf16x8*)(const void*)(abuf + r * 128 + ch * 8);
                hA[rt] = *(const bf16x8*)(const void*)(hbuf + r * 128 + ch * 8);
            }
#pragma unroll
            for (int g = 0; g < 3; ++g)
#pragma unroll
                for (int rt = 0; rt < 2; ++rt) {
                    gi[rt][g] = __builtin_amdgcn_mfma_f32_16x16x32_bf16(aA[rt], bI[ks][g], gi[rt][g], 0, 0, 0);
                    gh[rt][g] = __builtin_amdgcn_mfma_f32_16x16x32_bf16(hA[rt], bH[ks][g], gh[rt][g], 0, 0, 0);
                }
        }

        // GRU epilogue: g=0 -> r, g=1 -> z, g=2 -> n; hold re-read from h LDS
        long rowBase = tile * 32;
#pragma unroll
        for (int rt = 0; rt < 2; ++rt)
#pragma unroll
            for (int reg = 0; reg < 4; ++reg) {
                long row = rowBase + rt * 16 + quad * 4 + reg;
                if (row < N) {
                    int r2 = rt * 16 + quad * 4 + reg;
                    int hidx = r2 * 128 + ((((col >> 3) ^ (r2 & 7)) << 3) + (col & 7));
                    float R  = __builtin_amdgcn_rcpf(1.f + __expf(-(gi[rt][0][reg] + gh[rt][0][reg])));
                    float Z  = __builtin_amdgcn_rcpf(1.f + __expf(-(gi[rt][1][reg] + gh[rt][1][reg])));
                    float u  = gi[rt][2][reg] + R * gh[rt][2][reg];
                    float e2 = __expf(-2.f * fabsf(u));
                    float Nn = copysignf((1.f - e2) * __builtin_amdgcn_rcpf(1.f + e2), u);
                    float hold = bf2f(hbuf[hidx]);
                    hout[row * 128 + col] = f2bf((1.f - Z) * Nn + Z * hold);
                }
            }

        __builtin_amdgcn_s_barrier();   // all waves done reading cur before restage
        cur ^= 1;
    }
}

// ---------- CSR build pass 1: radix partition into coarse buckets ----------
__global__ __launch_bounds__(256) void part1_kernel(
    const int* __restrict__ ei, int E, const int* __restrict__ flags,
    int* __restrict__ gcnt, uint2* __restrict__ pair2,
    int nb, int cshift, int ccap, int chunk)
{
    __shared__ int cnt[256];
    __shared__ int base_s[256];
    const int tid = threadIdx.x;
    if (tid < nb) cnt[tid] = 0;
    __syncthreads();
    const bool i64 = flags[1] != 0;
    const long long* e64 = (const long long*)ei;
    int lo = blockIdx.x * chunk;
    int hi = lo + chunk; if (hi > E) hi = E;
    for (int i = lo + tid; i < hi; i += 256) {
        int d = i64 ? (int)e64[(long)E + i] : ei[(long)E + i];
        atomicAdd(&cnt[d >> cshift], 1);
    }
    __syncthreads();
    if (tid < nb) {
        int c = cnt[tid];
        base_s[tid] = (c > 0) ? atomicAdd(&gcnt[tid], c) : 0;
        cnt[tid] = 0;
    }
    __syncthreads();
    for (int i = lo + tid; i < hi; i += 256) {
        int s, d;
        if (i64) { s = (int)e64[i]; d = (int)e64[(long)E + i]; }
        else     { s = ei[i];       d = ei[(long)E + i]; }
        int c = d >> cshift;
        int p = base_s[c] + atomicAdd(&cnt[c], 1);
        if (p < ccap) { uint2 pr; pr.x = (unsigned)s; pr.y = (unsigned)d; pair2[(long)c * ccap + p] = pr; }
    }
}

// ---------- CSR build pass 2 (scan folded in): counting sort -> offs + csr ----------
// Each block redundantly scans the <=256 coarse-bucket counts (one-wave shfl
// scan into shared cb[]) -- eliminates the separate scanco launch.
__global__ __launch_bounds__(256) void part2_kernel(
    const uint2* __restrict__ pair2, const int* __restrict__ gcnt,
    int* __restrict__ offs, int* __restrict__ csr,
    int N, int nb, int cshift, int ccap)
{
    __shared__ int lb[2048];
    __shared__ int wsum[4];
    __shared__ int cb[257];
    const int b = blockIdx.x, tid = threadIdx.x;
    const int span = 1 << cshift;
    const int n0 = b << cshift;
    int lane = tid & 63, wv = tid >> 6;

    // ---- redundant exclusive scan of clamped gcnt into cb[] ----
    {
        int x = (tid < nb) ? gcnt[tid] : 0;
        if (x > ccap) x = ccap;
        int inc = x;
#pragma unroll
        for (int d = 1; d < 64; d <<= 1) { int u = __shfl_up(inc, d); if (lane >= d) inc += u; }
        if (lane == 63) wsum[wv] = inc;
        __syncthreads();
        if (tid == 0) { int s = 0; for (int q = 0; q < 4; ++q) { int t = wsum[q]; wsum[q] = s; s += t; } }
        __syncthreads();
        int excl = wsum[wv] + inc - x;
        if (tid < nb) cb[tid] = excl;
        if (tid == nb - 1) cb[nb] = excl + x;
    }
    __syncthreads();

    int count = gcnt[b]; if (count > ccap) count = ccap;
    for (int k = tid; k < span; k += 256) lb[k] = 0;
    __syncthreads();
    const uint2* pp = pair2 + (long)b * ccap;
    for (int i = tid; i < count; i += 256)
        atomicAdd(&lb[(int)pp[i].y - n0], 1);
    __syncthreads();
    int npe = span >> 8; if (npe < 1) npe = 1;
    int myb = tid * npe;
    int vals[8];
    int sum = 0;
    for (int k = 0; k < npe; ++k) { vals[k] = lb[myb + k]; sum += vals[k]; }
    int inc = sum;
#pragma unroll
    for (int d = 1; d < 64; d <<= 1) { int u = __shfl_up(inc, d); if (lane >= d) inc += u; }
    if (lane == 63) wsum[wv] = inc;
    __syncthreads();
    if (tid == 0) { int s = 0; for (int q = 0; q < 4; ++q) { int t = wsum[q]; wsum[q] = s; s += t; } }
    __syncthreads();
    int run = wsum[wv] + inc - sum;
    __syncthreads();
    for (int k = 0; k < npe; ++k) { lb[myb + k] = run; run += vals[k]; }
    __syncthreads();
    int gb = cb[b];
    int nn = N - n0; if (nn > span) nn = span;
    for (int g = tid; g < nn; g += 256) offs[n0 + g] = gb + lb[g];
    if (b == nb - 1 && tid == 0) offs[N] = cb[nb];
    __syncthreads();
    for (int i = tid; i < count; i += 256) {
        uint2 pr = pp[i];
        int p = gb + atomicAdd(&lb[(int)pr.y - n0], 1);
        csr[p] = (int)pr.x;
    }
}

// ---------- aggregation: persistent waves, contiguous node chunks ----------
// (pinned at the measured gather ceiling ~3.45 TB/s; do not touch)
__global__ __launch_bounds__(256) void aggregate(const unsigned short* __restrict__ hb,
                          const int* __restrict__ off,
                          const int* __restrict__ csr,
                          unsigned short* __restrict__ aggb, int n)
{
    int wv = threadIdx.x >> 6, lane = threadIdx.x & 63;
    int slot = lane >> 4;
    int c16 = lane & 15;
    int nw = gridDim.x * 4;                 // total waves
    int wid = blockIdx.x * 4 + wv;
    int chunk = (n + nw - 1) / nw;
    int lo = wid * chunk;
    int hi = lo + chunk; if (hi > n) hi = n;

    for (int node = lo; node < hi; ++node) {
        int s0 = off[node], s1 = off[node + 1];
        float a0 = 0.f, a1 = 0.f, a2 = 0.f, a3 = 0.f, a4 = 0.f, a5 = 0.f, a6 = 0.f, a7 = 0.f;
        if (s1 > s0) {
            int last = s1 - 1;
            for (int j = s0 + slot; j < s1; j += 16) {
                uint4 vv[4];
                float wt[4];
#pragma unroll
                for (int t = 0; t < 4; ++t) {
                    int jj = j + 4 * t;
                    int idx = csr[jj <= last ? jj : last];
                    vv[t] = *(const uint4*)(const void*)(hb + (long)idx * 128 + c16 * 8);
                    wt[t] = (jj <= last) ? 1.f : 0.f;
                }
#pragma unroll
                for (int t = 0; t < 4; ++t) {
                    a0 = fmaf(bflo(vv[t].x), wt[t], a0);
                    a1 = fmaf(bfhi(vv[t].x), wt[t], a1);
                    a2 = fmaf(bflo(vv[t].y), wt[t], a2);
                    a3 = fmaf(bfhi(vv[t].y), wt[t], a3);
                    a4 = fmaf(bflo(vv[t].z), wt[t], a4);
                    a5 = fmaf(bfhi(vv[t].z), wt[t], a5);
                    a6 = fmaf(bflo(vv[t].w), wt[t], a6);
                    a7 = fmaf(bfhi(vv[t].w), wt[t], a7);
                }
            }
        }
        a0 += __shfl_xor(a0, 16); a1 += __shfl_xor(a1, 16);
        a2 += __shfl_xor(a2, 16); a3 += __shfl_xor(a3, 16);
        a4 += __shfl_xor(a4, 16); a5 += __shfl_xor(a5, 16);
        a6 += __shfl_xor(a6, 16); a7 += __shfl_xor(a7, 16);
        a0 += __shfl_xor(a0, 32); a1 += __shfl_xor(a1, 32);
        a2 += __shfl_xor(a2, 32); a3 += __shfl_xor(a3, 32);
        a4 += __shfl_xor(a4, 32); a5 += __shfl_xor(a5, 32);
        a6 += __shfl_xor(a6, 32); a7 += __shfl_xor(a7, 32);
        if (slot == 0) {
            uint4 o;
            o.x = ((unsigned int)f2bf(a1) << 16) | f2bf(a0);
            o.y = ((unsigned int)f2bf(a3) << 16) | f2bf(a2);
            o.z = ((unsigned int)f2bf(a5) << 16) | f2bf(a4);
            o.w = ((unsigned int)f2bf(a7) << 16) | f2bf(a6);
            *(uint4*)(void*)(aggb + (long)node * 128 + c16 * 8) = o;
        }
    }
}

// ---------- readout: colsum with finalize folded in (last-block-done) ----------
__global__ void colsum_fin(const unsigned short* __restrict__ hb,
                           const float* __restrict__ Wpf,
                           const float* __restrict__ bpf,
                           unsigned int* __restrict__ out,
                           float* __restrict__ acc, int* __restrict__ done,
                           int n, float invN)
{
    __shared__ int isLast;
    __shared__ float ws2[2];
    int c = threadIdx.x & 127;
    int sub = threadIdx.x >> 7;
    float local = 0.f;
    for (long r = blockIdx.x * 2 + sub; r < n; r += (long)gridDim.x * 2) {
        float v = bf2f(hb[r * 128 + c]);
        local += (v >= 0.f) ? v : 0.01f * v;
    }
    atomicAdd(&acc[c], local);
    __threadfence();
    if (threadIdx.x == 0) {
        int d = atomicAdd(done, 1);
        isLast = (d == (int)gridDim.x - 1) ? 1 : 0;
    }
    __syncthreads();
    if (isLast) {
        float v = 0.f;
        if (threadIdx.x < 128) {
            // read through atomics: device-coherent view of other blocks' adds
            float a = atomicAdd(&acc[threadIdx.x], 0.f);
            v = a * invN * Wpf[threadIdx.x];
        }
#pragma unroll
        for (int d = 32; d >= 1; d >>= 1) v += __shfl_down(v, d);
        if (threadIdx.x < 128 && (threadIdx.x & 63) == 0) ws2[threadIdx.x >> 6] = v;
        __syncthreads();
        if (threadIdx.x == 0) {
            float r = ws2[0] + ws2[1] + bpf[0];
            unsigned int bfv = (unsigned int)f2bf(r);
            out[0] = (bfv << 16) | bfv;   // dual-dtype store
        }
    }
}

// ---------- host ----------
extern "C" void kernel_launch(void* const* d_in, const int* in_sizes, int n_in,
                              void* d_out, int out_size, void* d_ws, size_t ws_size,
                              hipStream_t stream)
{
    const void* x      = d_in[0];
    const int*  ei     = (const int*)d_in[1];
    const void* W_in   = d_in[2];
    const void* W_mpnn = d_in[3];
    const void* W_ih   = d_in[4];
    const void* W_hh   = d_in[5];
    const void* b_ih   = d_in[6];
    const void* b_hh   = d_in[7];
    const void* W_pred = d_in[8];
    const void* b_pred = d_in[9];

    const int N = in_sizes[0] / 64;              // 100000
    const int E = in_sizes[1] / 2;               // 1600000
    const int STEPS = in_sizes[3] / (128 * 128); // 4

    int cshift = 9;
    while ((((N + (1 << cshift) - 1) >> cshift)) > 256 && cshift < 11) cshift++;
    const int NCO = (N + (1 << cshift) - 1) >> cshift;
    const int ccap = (((E / NCO) * 3 / 2 + 1024) + 255) & ~255;
    const int chunk = (E + 255) / 256;

    size_t woff = 0;
    auto carve = [&](size_t bytes) -> void* {
        void* p = (char*)d_ws + woff;
        woff = (woff + bytes + 255) & ~(size_t)255;
        return p;
    };
    int*   flags = (int*)carve(2 * 4);
    float* Wpf   = (float*)carve(128 * 4);
    float* bpf   = (float*)carve(4);
    unsigned short* Bci = (unsigned short*)carve((size_t)STEPS * 49152 * 2);
    unsigned short* Bhh = (unsigned short*)carve(49152 * 2);
    unsigned short* Bin = (unsigned short*)carve(8192 * 2);
    float* bip   = (float*)carve(384 * 4);
    float* bhp   = (float*)carve(384 * 4);
    unsigned short* hA   = (unsigned short*)carve(((size_t)N * 128 + 16384) * 2);
    unsigned short* hB   = (unsigned short*)carve(((size_t)N * 128 + 16384) * 2);
    unsigned short* aggb = (unsigned short*)carve(((size_t)N * 128 + 16384) * 2);
    int*   offs  = (int*)carve((size_t)(N + 1) * 4);
    int*   csr   = (int*)carve((size_t)E * 4 + 256);
    uint2* pair2 = (uint2*)carve((size_t)NCO * ccap * 8);
    // zero-init region: gcnt | accb | done (contiguous carves -> ONE memset)
    int*   gcnt  = (int*)carve(256 * 4);
    float* accb  = (float*)carve(128 * 4);
    int*   done  = (int*)carve(4);
    size_t zbytes = (size_t)((char*)done - (char*)gcnt) + 256;

    hipMemsetAsync(gcnt, 0, zbytes, stream);

    {
        long total = (long)STEPS * 49152 + 49152 + 768 + 8192 + 128 + 1;
        int blocks = (int)((total + 255) / 256);
        prep_kernel<<<blocks, 256, 0, stream>>>(
            (const unsigned int*)x, ei, W_in, W_mpnn, W_ih, W_hh, b_ih, b_hh,
            W_pred, b_pred, Bci, Bhh, bip, bhp, Bin, Wpf, bpf, flags, STEPS);
    }

    // h0 = x @ W_in^T (reads raw x, runtime dtype)
    gemm_in<<<(N + 31) / 32, 256, 0, stream>>>(x, flags, Bin, hA, N);

    // CSR build: radix partition -> per-bucket counting sort (scan folded in)
    part1_kernel<<<256, 256, 0, stream>>>(ei, E, flags, gcnt, pair2, NCO, cshift, ccap, chunk);
    part2_kernel<<<NCO, 256, 0, stream>>>(pair2, gcnt, offs, csr, N, NCO, cshift, ccap);

    int aggBlocks = (N + 3) / 4; if (aggBlocks > 2048) aggBlocks = 2048;
    const int ntiles = (N + 31) / 32;
    int stepBlocks = ntiles < 256 ? ntiles : 256;
    unsigned short* hcur = hA;
    unsigned short* hnxt = hB;
    for (int step = 0; step < STEPS; ++step) {
        aggregate<<<aggBlocks, 256, 0, stream>>>(hcur, offs, csr, aggb, N);
        step_kernel<<<stepBlocks, 512, 0, stream>>>(
            hcur, aggb, Bci + (size_t)step * 49152, Bhh, bip, bhp, hnxt, N, ntiles);
        unsigned short* t = hcur; hcur = hnxt; hnxt = t;
    }

    colsum_fin<<<512, 256, 0, stream>>>(hcur, Wpf, bpf, (unsigned int*)d_out,
                                        accb, done, N, 1.f / (float)N);
}

// Round 11
// 601.434 us; speedup vs baseline: 1.0118x; 1.0014x over previous
//
#include <hip/hip_runtime.h>
#include <cstdint>

typedef __attribute__((ext_vector_type(8))) short bf16x8;
typedef __attribute__((ext_vector_type(4))) float f32x4;
typedef __attribute__((address_space(1))) unsigned int ga_u32;
typedef __attribute__((address_space(3))) unsigned int ls_u32;

// ---------- helpers ----------
__device__ __forceinline__ float bf2f(unsigned short u) {
    union { unsigned int i; float f; } v; v.i = ((unsigned int)u) << 16; return v.f;
}
__device__ __forceinline__ float bfhi(unsigned int w) {
    union { unsigned int i; float f; } v; v.i = w & 0xffff0000u; return v.f;
}
__device__ __forceinline__ float bflo(unsigned int w) {
    union { unsigned int i; float f; } v; v.i = w << 16; return v.f;
}
__device__ __forceinline__ unsigned short f2bf(float f) {
    union { float ff; unsigned int i; } v; v.ff = f;
    unsigned int r = (v.i + 0x7fffu + ((v.i >> 16) & 1u)) >> 16;
    return (unsigned short)r;
}
// gate-permuted column -> original column (nc in [0,384))
__device__ __forceinline__ int origcol(int nc) {
    int w = nc / 96, rem = nc % 96, g = rem / 32, cc = rem % 32;
    return g * 128 + w * 32 + cc;
}

// ---------- FUSED prep: detect + convert + wcomb-dot + pack (one launch) ----------
__global__ __launch_bounds__(256) void prep_kernel(
    const unsigned int* __restrict__ x32, const int* __restrict__ ei32,
    const void* W_in, const void* W_mpnn, const void* W_ih, const void* W_hh,
    const void* b_ih, const void* b_hh, const void* W_pred, const void* b_pred,
    unsigned short* __restrict__ Bci, unsigned short* __restrict__ Bhh,
    float* __restrict__ bip, float* __restrict__ bhp,
    unsigned short* __restrict__ Bin,
    float* __restrict__ Wpf, float* __restrict__ bpf,
    int* __restrict__ flags, int steps)
{
    __shared__ int insaneS, orS;
    const int tid = threadIdx.x;
    if (tid == 0) { insaneS = 0; orS = 0; }
    __syncthreads();
    {
        int insane = 0;
        for (int j = tid; j < 512; j += 256) {
            unsigned int w = x32[j];
            int e = (int)((w >> 7) & 0xFF);
            if (e > 135 || e < 100) insane++;
        }
        int ov = 0;
        for (int j = tid; j < 256; j += 256) ov |= ei32[2 * j + 1];
        atomicAdd(&insaneS, insane);
        atomicOr(&orS, ov);
    }
    __syncthreads();
    const bool bf = insaneS < 64;
    if (blockIdx.x == 0 && tid == 0) {
        flags[0] = bf ? 1 : 0;
        flags[1] = (orS == 0) ? 1 : 0;
    }

    auto cvt = [&](const void* p, long idx) -> float {
        return bf ? bf2f(((const unsigned short*)p)[idx]) : ((const float*)p)[idx];
    };

    const long n1 = (long)steps * 49152;       // Bci
    const long n2 = n1 + 49152;                // Bhh
    const long n3 = n2 + 768;                  // biases
    const long n4 = n3 + 8192;                 // Bin
    const long n5 = n4 + 128;                  // Wpf
    long i = (long)blockIdx.x * 256 + tid;

    if (i < n1) {
        int st = (int)(i / 49152), r = (int)(i - (long)st * 49152);
        int t = r >> 11, rem = r & 2047;
        int ks = rem >> 9, l = (rem >> 3) & 63, j = rem & 7;
        int k = ks * 32 + (l >> 4) * 8 + j;
        int oc = origcol(t * 16 + (l & 15));
        float s = 0.f;
        if (bf) {
            const unsigned short* wm = (const unsigned short*)W_mpnn + ((long)st * 128 + k) * 128;
            const unsigned short* wi = (const unsigned short*)W_ih + (long)oc * 128;
#pragma unroll 4
            for (int tt = 0; tt < 128; tt += 8) {
                uint4 a = *(const uint4*)(const void*)(wm + tt);
                uint4 b = *(const uint4*)(const void*)(wi + tt);
                s += bflo(a.x) * bflo(b.x) + bfhi(a.x) * bfhi(b.x);
                s += bflo(a.y) * bflo(b.y) + bfhi(a.y) * bfhi(b.y);
                s += bflo(a.z) * bflo(b.z) + bfhi(a.z) * bfhi(b.z);
                s += bflo(a.w) * bflo(b.w) + bfhi(a.w) * bfhi(b.w);
            }
        } else {
            const float* wm = (const float*)W_mpnn + ((long)st * 128 + k) * 128;
            const float* wi = (const float*)W_ih + (long)oc * 128;
#pragma unroll 4
            for (int tt = 0; tt < 128; tt += 4) {
                float4 a = *(const float4*)(wm + tt);
                float4 b = *(const float4*)(wi + tt);
                s += a.x * b.x + a.y * b.y + a.z * b.z + a.w * b.w;
            }
        }
        Bci[i] = f2bf(s);
    } else if (i < n2) {
        int r = (int)(i - n1);
        int t = r >> 11, rem = r & 2047;
        int ks = rem >> 9, l = (rem >> 3) & 63, j = rem & 7;
        int k = ks * 32 + (l >> 4) * 8 + j;
        int oc = origcol(t * 16 + (l & 15));
        Bhh[r] = f2bf(cvt(W_hh, (long)oc * 128 + k));
    } else if (i < n3) {
        int b = (int)(i - n2);
        if (b < 384) bip[b] = cvt(b_ih, origcol(b));
        else         bhp[b - 384] = cvt(b_hh, origcol(b - 384));
    } else if (i < n4) {
        int r = (int)(i - n3);
        int t = r >> 10, rem = r & 1023;
        int ks = rem >> 9, l = (rem >> 3) & 63, j = rem & 7;
        int k = ks * 32 + (l >> 4) * 8 + j;
        int col = t * 16 + (l & 15);
        Bin[r] = f2bf(cvt(W_in, col * 64 + k));
    } else if (i < n5) {
        int idx = (int)(i - n4);
        Wpf[idx] = cvt(W_pred, idx);
    } else if (i == n5) {
        bpf[0] = cvt(b_pred, 0);
    }
}

// ---------- input embedding: h = x @ W_in^T (MFMA, raw x w/ runtime dtype) ----------
__global__ __launch_bounds__(256) void gemm_in(const void* __restrict__ xraw,
                        const int* __restrict__ flags,
                        const unsigned short* __restrict__ Bin,
                        unsigned short* __restrict__ hout, int N)
{
    const int w = threadIdx.x >> 6, lane = threadIdx.x & 63;
    const int m = lane & 15, quad = lane >> 4;
    const int rowBase = blockIdx.x * 32;
    const bool abf = flags[0] != 0;
    f32x4 acc[2][2];
#pragma unroll
    for (int rt = 0; rt < 2; ++rt)
#pragma unroll
        for (int ct = 0; ct < 2; ++ct) acc[rt][ct] = (f32x4){0.f, 0.f, 0.f, 0.f};

#pragma unroll
    for (int ks = 0; ks < 2; ++ks) {
        bf16x8 a[2];
#pragma unroll
        for (int rt = 0; rt < 2; ++rt) {
            long row = rowBase + rt * 16 + m;
            if (abf) {
                a[rt] = *(const bf16x8*)(const void*)((const unsigned short*)xraw + row * 64 + ks * 32 + quad * 8);
            } else {
                const float* xp = (const float*)xraw + row * 64 + ks * 32 + quad * 8;
                float4 f0 = *(const float4*)xp;
                float4 f1 = *(const float4*)(xp + 4);
                bf16x8 t;
                t[0] = (short)f2bf(f0.x); t[1] = (short)f2bf(f0.y);
                t[2] = (short)f2bf(f0.z); t[3] = (short)f2bf(f0.w);
                t[4] = (short)f2bf(f1.x); t[5] = (short)f2bf(f1.y);
                t[6] = (short)f2bf(f1.z); t[7] = (short)f2bf(f1.w);
                a[rt] = t;
            }
        }
#pragma unroll
        for (int ct = 0; ct < 2; ++ct) {
            int t = w * 2 + ct;
            bf16x8 b = *(const bf16x8*)(const void*)(Bin + ((t * 2 + ks) * 64 + lane) * 8);
#pragma unroll
            for (int rt = 0; rt < 2; ++rt)
                acc[rt][ct] = __builtin_amdgcn_mfma_f32_16x16x32_bf16(a[rt], b, acc[rt][ct], 0, 0, 0);
        }
    }
#pragma unroll
    for (int rt = 0; rt < 2; ++rt)
#pragma unroll
        for (int ct = 0; ct < 2; ++ct)
#pragma unroll
            for (int reg = 0; reg < 4; ++reg) {
                int row = rowBase + rt * 16 + quad * 4 + reg;
                int col = w * 32 + ct * 16 + m;
                if (row < N) hout[(long)row * 128 + col] = f2bf(acc[rt][ct][reg]);
            }
}

// ---------- MPNN+GRU step: PERSISTENT blocks, B resident (round-8 best) ----------
__global__ __launch_bounds__(512, 2) void step_kernel(
    const unsigned short* __restrict__ hin,
    const unsigned short* __restrict__ aggb,
    const unsigned short* __restrict__ Bci,
    const unsigned short* __restrict__ Bhh,
    const float* __restrict__ bip, const float* __restrict__ bhp,
    unsigned short* __restrict__ hout, int N, int ntiles)
{
    __shared__ unsigned short lds[16384];  // 2 bufs x (agg[4096] | h[4096]) shorts
    const int tid = threadIdx.x;
    const int w = tid >> 6, lane = tid & 63;
    const int m = lane & 15, quad = lane >> 4;
    const int cg = w >> 1, half = w & 1;
    const int col = cg * 32 + half * 16 + m;
    const int grid = gridDim.x;

    // ---- resident B fragments (loaded once) ----
    bf16x8 bI[4][3], bH[4][3];
#pragma unroll
    for (int ks = 0; ks < 4; ++ks)
#pragma unroll
        for (int g = 0; g < 3; ++g) {
            int t = cg * 6 + g * 2 + half;
            bI[ks][g] = *(const bf16x8*)(const void*)(Bci + (((long)t * 4 + ks) * 64 + lane) * 8);
            bH[ks][g] = *(const bf16x8*)(const void*)(Bhh + (((long)t * 4 + ks) * 64 + lane) * 8);
        }
    // ---- resident biases ----
    float bi0[3], bh0[3];
#pragma unroll
    for (int g = 0; g < 3; ++g) {
        int nc = (cg * 6 + g * 2 + half) * 16 + m;
        bi0[g] = bip[nc]; bh0[g] = bhp[nc];
    }

    // staging geometry (constant per thread)
    const int lrow = w * 4 + (lane >> 4);           // tile row of this lane's 16B
    const int schunk = (lane & 15) ^ (lrow & 7);    // XOR-swizzled source chunk

    long tile = blockIdx.x;
    int cur = 0;
    if (tile < ntiles) {
        const unsigned short* gap = aggb + (tile * 32 + lrow) * 128 + schunk * 8;
        const unsigned short* ghp = hin  + (tile * 32 + lrow) * 128 + schunk * 8;
        __builtin_amdgcn_global_load_lds((const ga_u32*)gap, (ls_u32*)(lds + w * 512), 16, 0, 0);
        __builtin_amdgcn_global_load_lds((const ga_u32*)ghp, (ls_u32*)(lds + 4096 + w * 512), 16, 0, 0);
    }

    for (; tile < ntiles; tile += grid) {
        long nxt = tile + grid;
        bool hasNext = nxt < ntiles;
        if (hasNext) {
            int nb = cur ^ 1;
            const unsigned short* gap = aggb + (nxt * 32 + lrow) * 128 + schunk * 8;
            const unsigned short* ghp = hin  + (nxt * 32 + lrow) * 128 + schunk * 8;
            __builtin_amdgcn_global_load_lds((const ga_u32*)gap, (ls_u32*)(lds + nb * 8192 + w * 512), 16, 0, 0);
            __builtin_amdgcn_global_load_lds((const ga_u32*)ghp, (ls_u32*)(lds + nb * 8192 + 4096 + w * 512), 16, 0, 0);
            asm volatile("s_waitcnt vmcnt(2)" ::: "memory");
        } else {
            asm volatile("s_waitcnt vmcnt(0)" ::: "memory");
        }
        __builtin_amdgcn_s_barrier();

        const unsigned short* abuf = lds + cur * 8192;
        const unsigned short* hbuf = lds + cur * 8192 + 4096;

        // accumulators (bias-initialized)
        f32x4 gi[2][3], gh[2][3];
#pragma unroll
        for (int g = 0; g < 3; ++g)
#pragma unroll
            for (int rt = 0; rt < 2; ++rt) {
                gi[rt][g] = (f32x4){bi0[g], bi0[g], bi0[g], bi0[g]};
                gh[rt][g] = (f32x4){bh0[g], bh0[g], bh0[g], bh0[g]};
            }

#pragma unroll
        for (int ks = 0; ks < 4; ++ks) {
            bf16x8 aA[2], hA[2];
#pragma unroll
            for (int rt = 0; rt < 2; ++rt) {
                int r = rt * 16 + m;
                int ch = (ks * 4 + quad) ^ (r & 7);
                aA[rt] = *(const bf16x8*)(const void*)(abuf + r * 128 + ch * 8);
                hA[rt] = *(const bf16x8*)(const void*)(hbuf + r * 128 + ch * 8);
            }
#pragma unroll
            for (int g = 0; g < 3; ++g)
#pragma unroll
                for (int rt = 0; rt < 2; ++rt) {
                    gi[rt][g] = __builtin_amdgcn_mfma_f32_16x16x32_bf16(aA[rt], bI[ks][g], gi[rt][g], 0, 0, 0);
                    gh[rt][g] = __builtin_amdgcn_mfma_f32_16x16x32_bf16(hA[rt], bH[ks][g], gh[rt][g], 0, 0, 0);
                }
        }

        // GRU epilogue: g=0 -> r, g=1 -> z, g=2 -> n; hold re-read from h LDS
        long rowBase = tile * 32;
#pragma unroll
        for (int rt = 0; rt < 2; ++rt)
#pragma unroll
            for (int reg = 0; reg < 4; ++reg) {
                long row = rowBase + rt * 16 + quad * 4 + reg;
                if (row < N) {
                    int r2 = rt * 16 + quad * 4 + reg;
                    int hidx = r2 * 128 + ((((col >> 3) ^ (r2 & 7)) << 3) + (col & 7));
                    float R  = __builtin_amdgcn_rcpf(1.f + __expf(-(gi[rt][0][reg] + gh[rt][0][reg])));
                    float Z  = __builtin_amdgcn_rcpf(1.f + __expf(-(gi[rt][1][reg] + gh[rt][1][reg])));
                    float u  = gi[rt][2][reg] + R * gh[rt][2][reg];
                    float e2 = __expf(-2.f * fabsf(u));
                    float Nn = copysignf((1.f - e2) * __builtin_amdgcn_rcpf(1.f + e2), u);
                    float hold = bf2f(hbuf[hidx]);
                    hout[row * 128 + col] = f2bf((1.f - Z) * Nn + Z * hold);
                }
            }

        __builtin_amdgcn_s_barrier();   // all waves done reading cur before restage
        cur ^= 1;
    }
}

// ---------- CSR build pass 1: radix partition into coarse buckets ----------
__global__ __launch_bounds__(256) void part1_kernel(
    const int* __restrict__ ei, int E, const int* __restrict__ flags,
    int* __restrict__ gcnt, uint2* __restrict__ pair2,
    int nb, int cshift, int ccap, int chunk)
{
    __shared__ int cnt[256];
    __shared__ int base_s[256];
    const int tid = threadIdx.x;
    if (tid < nb) cnt[tid] = 0;
    __syncthreads();
    const bool i64 = flags[1] != 0;
    const long long* e64 = (const long long*)ei;
    int lo = blockIdx.x * chunk;
    int hi = lo + chunk; if (hi > E) hi = E;
    for (int i = lo + tid; i < hi; i += 256) {
        int d = i64 ? (int)e64[(long)E + i] : ei[(long)E + i];
        atomicAdd(&cnt[d >> cshift], 1);
    }
    __syncthreads();
    if (tid < nb) {
        int c = cnt[tid];
        base_s[tid] = (c > 0) ? atomicAdd(&gcnt[tid], c) : 0;
        cnt[tid] = 0;
    }
    __syncthreads();
    for (int i = lo + tid; i < hi; i += 256) {
        int s, d;
        if (i64) { s = (int)e64[i]; d = (int)e64[(long)E + i]; }
        else     { s = ei[i];       d = ei[(long)E + i]; }
        int c = d >> cshift;
        int p = base_s[c] + atomicAdd(&cnt[c], 1);
        if (p < ccap) { uint2 pr; pr.x = (unsigned)s; pr.y = (unsigned)d; pair2[(long)c * ccap + p] = pr; }
    }
}

// ---------- CSR build pass 2 (scan folded in): counting sort -> offs + csr ----------
__global__ __launch_bounds__(256) void part2_kernel(
    const uint2* __restrict__ pair2, const int* __restrict__ gcnt,
    int* __restrict__ offs, int* __restrict__ csr,
    int N, int nb, int cshift, int ccap)
{
    __shared__ int lb[2048];
    __shared__ int wsum[4];
    __shared__ int cb[257];
    const int b = blockIdx.x, tid = threadIdx.x;
    const int span = 1 << cshift;
    const int n0 = b << cshift;
    int lane = tid & 63, wv = tid >> 6;

    // ---- redundant exclusive scan of clamped gcnt into cb[] ----
    {
        int x = (tid < nb) ? gcnt[tid] : 0;
        if (x > ccap) x = ccap;
        int inc = x;
#pragma unroll
        for (int d = 1; d < 64; d <<= 1) { int u = __shfl_up(inc, d); if (lane >= d) inc += u; }
        if (lane == 63) wsum[wv] = inc;
        __syncthreads();
        if (tid == 0) { int s = 0; for (int q = 0; q < 4; ++q) { int t = wsum[q]; wsum[q] = s; s += t; } }
        __syncthreads();
        int excl = wsum[wv] + inc - x;
        if (tid < nb) cb[tid] = excl;
        if (tid == nb - 1) cb[nb] = excl + x;
    }
    __syncthreads();

    int count = gcnt[b]; if (count > ccap) count = ccap;
    for (int k = tid; k < span; k += 256) lb[k] = 0;
    __syncthreads();
    const uint2* pp = pair2 + (long)b * ccap;
    for (int i = tid; i < count; i += 256)
        atomicAdd(&lb[(int)pp[i].y - n0], 1);
    __syncthreads();
    int npe = span >> 8; if (npe < 1) npe = 1;
    int myb = tid * npe;
    int vals[8];
    int sum = 0;
    for (int k = 0; k < npe; ++k) { vals[k] = lb[myb + k]; sum += vals[k]; }
    int inc = sum;
#pragma unroll
    for (int d = 1; d < 64; d <<= 1) { int u = __shfl_up(inc, d); if (lane >= d) inc += u; }
    if (lane == 63) wsum[wv] = inc;
    __syncthreads();
    if (tid == 0) { int s = 0; for (int q = 0; q < 4; ++q) { int t = wsum[q]; wsum[q] = s; s += t; } }
    __syncthreads();
    int run = wsum[wv] + inc - sum;
    __syncthreads();
    for (int k = 0; k < npe; ++k) { lb[myb + k] = run; run += vals[k]; }
    __syncthreads();
    int gb = cb[b];
    int nn = N - n0; if (nn > span) nn = span;
    for (int g = tid; g < nn; g += 256) offs[n0 + g] = gb + lb[g];
    if (b == nb - 1 && tid == 0) offs[N] = cb[nb];
    __syncthreads();
    for (int i = tid; i < count; i += 256) {
        uint2 pr = pp[i];
        int p = gb + atomicAdd(&lb[(int)pr.y - n0], 1);
        csr[p] = (int)pr.x;
    }
}

// ---------- aggregation: persistent waves, contiguous node chunks ----------
// (pinned at the measured gather ceiling ~3.45 TB/s; do not touch)
__global__ __launch_bounds__(256) void aggregate(const unsigned short* __restrict__ hb,
                          const int* __restrict__ off,
                          const int* __restrict__ csr,
                          unsigned short* __restrict__ aggb, int n)
{
    int wv = threadIdx.x >> 6, lane = threadIdx.x & 63;
    int slot = lane >> 4;
    int c16 = lane & 15;
    int nw = gridDim.x * 4;                 // total waves
    int wid = blockIdx.x * 4 + wv;
    int chunk = (n + nw - 1) / nw;
    int lo = wid * chunk;
    int hi = lo + chunk; if (hi > n) hi = n;

    for (int node = lo; node < hi; ++node) {
        int s0 = off[node], s1 = off[node + 1];
        float a0 = 0.f, a1 = 0.f, a2 = 0.f, a3 = 0.f, a4 = 0.f, a5 = 0.f, a6 = 0.f, a7 = 0.f;
        if (s1 > s0) {
            int last = s1 - 1;
            for (int j = s0 + slot; j < s1; j += 16) {
                uint4 vv[4];
                float wt[4];
#pragma unroll
                for (int t = 0; t < 4; ++t) {
                    int jj = j + 4 * t;
                    int idx = csr[jj <= last ? jj : last];
                    vv[t] = *(const uint4*)(const void*)(hb + (long)idx * 128 + c16 * 8);
                    wt[t] = (jj <= last) ? 1.f : 0.f;
                }
#pragma unroll
                for (int t = 0; t < 4; ++t) {
                    a0 = fmaf(bflo(vv[t].x), wt[t], a0);
                    a1 = fmaf(bfhi(vv[t].x), wt[t], a1);
                    a2 = fmaf(bflo(vv[t].y), wt[t], a2);
                    a3 = fmaf(bfhi(vv[t].y), wt[t], a3);
                    a4 = fmaf(bflo(vv[t].z), wt[t], a4);
                    a5 = fmaf(bfhi(vv[t].z), wt[t], a5);
                    a6 = fmaf(bflo(vv[t].w), wt[t], a6);
                    a7 = fmaf(bfhi(vv[t].w), wt[t], a7);
                }
            }
        }
        a0 += __shfl_xor(a0, 16); a1 += __shfl_xor(a1, 16);
        a2 += __shfl_xor(a2, 16); a3 += __shfl_xor(a3, 16);
        a4 += __shfl_xor(a4, 16); a5 += __shfl_xor(a5, 16);
        a6 += __shfl_xor(a6, 16); a7 += __shfl_xor(a7, 16);
        a0 += __shfl_xor(a0, 32); a1 += __shfl_xor(a1, 32);
        a2 += __shfl_xor(a2, 32); a3 += __shfl_xor(a3, 32);
        a4 += __shfl_xor(a4, 32); a5 += __shfl_xor(a5, 32);
        a6 += __shfl_xor(a6, 32); a7 += __shfl_xor(a7, 32);
        if (slot == 0) {
            uint4 o;
            o.x = ((unsigned int)f2bf(a1) << 16) | f2bf(a0);
            o.y = ((unsigned int)f2bf(a3) << 16) | f2bf(a2);
            o.z = ((unsigned int)f2bf(a5) << 16) | f2bf(a4);
            o.w = ((unsigned int)f2bf(a7) << 16) | f2bf(a6);
            *(uint4*)(void*)(aggb + (long)node * 128 + c16 * 8) = o;
        }
    }
}

// ---------- readout: VECTORIZED colsum + finalize (last-block-done) ----------
// 16B/lane uint4 loads (G13): 16 threads cover a row, block covers 16 rows/iter.
// Per-thread 8-col register accumulators -> LDS-atomic block reduce -> one
// global atomicAdd per column per block. Was 67us with scalar 2B loads.
__global__ __launch_bounds__(256) void colsum_fin(const unsigned short* __restrict__ hb,
                           const float* __restrict__ Wpf,
                           const float* __restrict__ bpf,
                           unsigned int* __restrict__ out,
                           float* __restrict__ acc, int* __restrict__ done,
                           int n, float invN)
{
    __shared__ float sacc[128];
    __shared__ int isLast;
    __shared__ float ws2[2];
    const int tid = threadIdx.x;
    const int c16 = tid & 15;      // which 16B chunk within the row
    const int rsub = tid >> 4;     // row within the 16-row group
    if (tid < 128) sacc[tid] = 0.f;
    __syncthreads();

    float a0 = 0.f, a1 = 0.f, a2 = 0.f, a3 = 0.f,
          a4 = 0.f, a5 = 0.f, a6 = 0.f, a7 = 0.f;
    long groups = ((long)n + 15) >> 4;
    for (long g = blockIdx.x; g < groups; g += gridDim.x) {
        long row = g * 16 + rsub;
        if (row < n) {
            uint4 v = *(const uint4*)(const void*)(hb + row * 128 + c16 * 8);
            float x;
            x = bflo(v.x); a0 += (x >= 0.f) ? x : 0.01f * x;
            x = bfhi(v.x); a1 += (x >= 0.f) ? x : 0.01f * x;
            x = bflo(v.y); a2 += (x >= 0.f) ? x : 0.01f * x;
            x = bfhi(v.y); a3 += (x >= 0.f) ? x : 0.01f * x;
            x = bflo(v.z); a4 += (x >= 0.f) ? x : 0.01f * x;
            x = bfhi(v.z); a5 += (x >= 0.f) ? x : 0.01f * x;
            x = bflo(v.w); a6 += (x >= 0.f) ? x : 0.01f * x;
            x = bfhi(v.w); a7 += (x >= 0.f) ? x : 0.01f * x;
        }
    }
    int cb = c16 * 8;
    atomicAdd(&sacc[cb + 0], a0); atomicAdd(&sacc[cb + 1], a1);
    atomicAdd(&sacc[cb + 2], a2); atomicAdd(&sacc[cb + 3], a3);
    atomicAdd(&sacc[cb + 4], a4); atomicAdd(&sacc[cb + 5], a5);
    atomicAdd(&sacc[cb + 6], a6); atomicAdd(&sacc[cb + 7], a7);
    __syncthreads();
    if (tid < 128) atomicAdd(&acc[tid], sacc[tid]);
    __threadfence();
    if (tid == 0) {
        int d = atomicAdd(done, 1);
        isLast = (d == (int)gridDim.x - 1) ? 1 : 0;
    }
    __syncthreads();
    if (isLast) {
        float v = 0.f;
        if (tid < 128) {
            // read through atomics: device-coherent view of other blocks' adds
            float a = atomicAdd(&acc[tid], 0.f);
            v = a * invN * Wpf[tid];
        }
#pragma unroll
        for (int d = 32; d >= 1; d >>= 1) v += __shfl_down(v, d);
        if (tid < 128 && (tid & 63) == 0) ws2[tid >> 6] = v;
        __syncthreads();
        if (tid == 0) {
            float r = ws2[0] + ws2[1] + bpf[0];
            unsigned int bfv = (unsigned int)f2bf(r);
            out[0] = (bfv << 16) | bfv;   // dual-dtype store
        }
    }
}

// ---------- host ----------
extern "C" void kernel_launch(void* const* d_in, const int* in_sizes, int n_in,
                              void* d_out, int out_size, void* d_ws, size_t ws_size,
                              hipStream_t stream)
{
    const void* x      = d_in[0];
    const int*  ei     = (const int*)d_in[1];
    const void* W_in   = d_in[2];
    const void* W_mpnn = d_in[3];
    const void* W_ih   = d_in[4];
    const void* W_hh   = d_in[5];
    const void* b_ih   = d_in[6];
    const void* b_hh   = d_in[7];
    const void* W_pred = d_in[8];
    const void* b_pred = d_in[9];

    const int N = in_sizes[0] / 64;              // 100000
    const int E = in_sizes[1] / 2;               // 1600000
    const int STEPS = in_sizes[3] / (128 * 128); // 4

    int cshift = 9;
    while ((((N + (1 << cshift) - 1) >> cshift)) > 256 && cshift < 11) cshift++;
    const int NCO = (N + (1 << cshift) - 1) >> cshift;
    const int ccap = (((E / NCO) * 3 / 2 + 1024) + 255) & ~255;
    const int chunk = (E + 255) / 256;

    size_t woff = 0;
    auto carve = [&](size_t bytes) -> void* {
        void* p = (char*)d_ws + woff;
        woff = (woff + bytes + 255) & ~(size_t)255;
        return p;
    };
    int*   flags = (int*)carve(2 * 4);
    float* Wpf   = (float*)carve(128 * 4);
    float* bpf   = (float*)carve(4);
    unsigned short* Bci = (unsigned short*)carve((size_t)STEPS * 49152 * 2);
    unsigned short* Bhh = (unsigned short*)carve(49152 * 2);
    unsigned short* Bin = (unsigned short*)carve(8192 * 2);
    float* bip   = (float*)carve(384 * 4);
    float* bhp   = (float*)carve(384 * 4);
    unsigned short* hA   = (unsigned short*)carve(((size_t)N * 128 + 16384) * 2);
    unsigned short* hB   = (unsigned short*)carve(((size_t)N * 128 + 16384) * 2);
    unsigned short* aggb = (unsigned short*)carve(((size_t)N * 128 + 16384) * 2);
    int*   offs  = (int*)carve((size_t)(N + 1) * 4);
    int*   csr   = (int*)carve((size_t)E * 4 + 256);
    uint2* pair2 = (uint2*)carve((size_t)NCO * ccap * 8);
    // zero-init region: gcnt | accb | done (contiguous carves -> ONE memset)
    int*   gcnt  = (int*)carve(256 * 4);
    float* accb  = (float*)carve(128 * 4);
    int*   done  = (int*)carve(4);
    size_t zbytes = (size_t)((char*)done - (char*)gcnt) + 256;

    hipMemsetAsync(gcnt, 0, zbytes, stream);

    {
        long total = (long)STEPS * 49152 + 49152 + 768 + 8192 + 128 + 1;
        int blocks = (int)((total + 255) / 256);
        prep_kernel<<<blocks, 256, 0, stream>>>(
            (const unsigned int*)x, ei, W_in, W_mpnn, W_ih, W_hh, b_ih, b_hh,
            W_pred, b_pred, Bci, Bhh, bip, bhp, Bin, Wpf, bpf, flags, STEPS);
    }

    // h0 = x @ W_in^T (reads raw x, runtime dtype)
    gemm_in<<<(N + 31) / 32, 256, 0, stream>>>(x, flags, Bin, hA, N);

    // CSR build: radix partition -> per-bucket counting sort (scan folded in)
    part1_kernel<<<256, 256, 0, stream>>>(ei, E, flags, gcnt, pair2, NCO, cshift, ccap, chunk);
    part2_kernel<<<NCO, 256, 0, stream>>>(pair2, gcnt, offs, csr, N, NCO, cshift, ccap);

    int aggBlocks = (N + 3) / 4; if (aggBlocks > 2048) aggBlocks = 2048;
    const int ntiles = (N + 31) / 32;
    int stepBlocks = ntiles < 256 ? ntiles : 256;
    unsigned short* hcur = hA;
    unsigned short* hnxt = hB;
    for (int step = 0; step < STEPS; ++step) {
        aggregate<<<aggBlocks, 256, 0, stream>>>(hcur, offs, csr, aggb, N);
        step_kernel<<<stepBlocks, 512, 0, stream>>>(
            hcur, aggb, Bci + (size_t)step * 49152, Bhh, bip, bhp, hnxt, N, ntiles);
        unsigned short* t = hcur; hcur = hnxt; hnxt = t;
    }

    colsum_fin<<<1024, 256, 0, stream>>>(hcur, Wpf, bpf, (unsigned int*)d_out,
                                         accb, done, N, 1.f / (float)N);
}

// Round 12
// 543.149 us; speedup vs baseline: 1.1203x; 1.1073x over previous
//
#include <hip/hip_runtime.h>
#include <cstdint>

typedef __attribute__((ext_vector_type(8))) short bf16x8;
typedef __attribute__((ext_vector_type(4))) float f32x4;
typedef __attribute__((address_space(1))) unsigned int ga_u32;
typedef __attribute__((address_space(3))) unsigned int ls_u32;

// ---------- helpers ----------
__device__ __forceinline__ float bf2f(unsigned short u) {
    union { unsigned int i; float f; } v; v.i = ((unsigned int)u) << 16; return v.f;
}
__device__ __forceinline__ float bfhi(unsigned int w) {
    union { unsigned int i; float f; } v; v.i = w & 0xffff0000u; return v.f;
}
__device__ __forceinline__ float bflo(unsigned int w) {
    union { unsigned int i; float f; } v; v.i = w << 16; return v.f;
}
__device__ __forceinline__ unsigned short f2bf(float f) {
    union { float ff; unsigned int i; } v; v.ff = f;
    unsigned int r = (v.i + 0x7fffu + ((v.i >> 16) & 1u)) >> 16;
    return (unsigned short)r;
}
// gate-permuted column -> original column (nc in [0,384))
__device__ __forceinline__ int origcol(int nc) {
    int w = nc / 96, rem = nc % 96, g = rem / 32, cc = rem % 32;
    return g * 128 + w * 32 + cc;
}

// ---------- FUSED prep: detect + convert + wcomb-dot + pack (one launch) ----------
__global__ __launch_bounds__(256) void prep_kernel(
    const unsigned int* __restrict__ x32, const int* __restrict__ ei32,
    const void* W_in, const void* W_mpnn, const void* W_ih, const void* W_hh,
    const void* b_ih, const void* b_hh, const void* W_pred, const void* b_pred,
    unsigned short* __restrict__ Bci, unsigned short* __restrict__ Bhh,
    float* __restrict__ bip, float* __restrict__ bhp,
    unsigned short* __restrict__ Bin,
    float* __restrict__ Wpf, float* __restrict__ bpf,
    int* __restrict__ flags, int steps)
{
    __shared__ int insaneS, orS;
    const int tid = threadIdx.x;
    if (tid == 0) { insaneS = 0; orS = 0; }
    __syncthreads();
    {
        int insane = 0;
        for (int j = tid; j < 512; j += 256) {
            unsigned int w = x32[j];
            int e = (int)((w >> 7) & 0xFF);
            if (e > 135 || e < 100) insane++;
        }
        int ov = 0;
        for (int j = tid; j < 256; j += 256) ov |= ei32[2 * j + 1];
        atomicAdd(&insaneS, insane);
        atomicOr(&orS, ov);
    }
    __syncthreads();
    const bool bf = insaneS < 64;
    if (blockIdx.x == 0 && tid == 0) {
        flags[0] = bf ? 1 : 0;
        flags[1] = (orS == 0) ? 1 : 0;
    }

    auto cvt = [&](const void* p, long idx) -> float {
        return bf ? bf2f(((const unsigned short*)p)[idx]) : ((const float*)p)[idx];
    };

    const long n1 = (long)steps * 49152;       // Bci
    const long n2 = n1 + 49152;                // Bhh
    const long n3 = n2 + 768;                  // biases
    const long n4 = n3 + 8192;                 // Bin
    const long n5 = n4 + 128;                  // Wpf
    long i = (long)blockIdx.x * 256 + tid;

    if (i < n1) {
        int st = (int)(i / 49152), r = (int)(i - (long)st * 49152);
        int t = r >> 11, rem = r & 2047;
        int ks = rem >> 9, l = (rem >> 3) & 63, j = rem & 7;
        int k = ks * 32 + (l >> 4) * 8 + j;
        int oc = origcol(t * 16 + (l & 15));
        float s = 0.f;
        if (bf) {
            const unsigned short* wm = (const unsigned short*)W_mpnn + ((long)st * 128 + k) * 128;
            const unsigned short* wi = (const unsigned short*)W_ih + (long)oc * 128;
#pragma unroll 4
            for (int tt = 0; tt < 128; tt += 8) {
                uint4 a = *(const uint4*)(const void*)(wm + tt);
                uint4 b = *(const uint4*)(const void*)(wi + tt);
                s += bflo(a.x) * bflo(b.x) + bfhi(a.x) * bfhi(b.x);
                s += bflo(a.y) * bflo(b.y) + bfhi(a.y) * bfhi(b.y);
                s += bflo(a.z) * bflo(b.z) + bfhi(a.z) * bfhi(b.z);
                s += bflo(a.w) * bflo(b.w) + bfhi(a.w) * bfhi(b.w);
            }
        } else {
            const float* wm = (const float*)W_mpnn + ((long)st * 128 + k) * 128;
            const float* wi = (const float*)W_ih + (long)oc * 128;
#pragma unroll 4
            for (int tt = 0; tt < 128; tt += 4) {
                float4 a = *(const float4*)(wm + tt);
                float4 b = *(const float4*)(wi + tt);
                s += a.x * b.x + a.y * b.y + a.z * b.z + a.w * b.w;
            }
        }
        Bci[i] = f2bf(s);
    } else if (i < n2) {
        int r = (int)(i - n1);
        int t = r >> 11, rem = r & 2047;
        int ks = rem >> 9, l = (rem >> 3) & 63, j = rem & 7;
        int k = ks * 32 + (l >> 4) * 8 + j;
        int oc = origcol(t * 16 + (l & 15));
        Bhh[r] = f2bf(cvt(W_hh, (long)oc * 128 + k));
    } else if (i < n3) {
        int b = (int)(i - n2);
        if (b < 384) bip[b] = cvt(b_ih, origcol(b));
        else         bhp[b - 384] = cvt(b_hh, origcol(b - 384));
    } else if (i < n4) {
        int r = (int)(i - n3);
        int t = r >> 10, rem = r & 1023;
        int ks = rem >> 9, l = (rem >> 3) & 63, j = rem & 7;
        int k = ks * 32 + (l >> 4) * 8 + j;
        int col = t * 16 + (l & 15);
        Bin[r] = f2bf(cvt(W_in, col * 64 + k));
    } else if (i < n5) {
        int idx = (int)(i - n4);
        Wpf[idx] = cvt(W_pred, idx);
    } else if (i == n5) {
        bpf[0] = cvt(b_pred, 0);
    }
}

// ---------- input embedding: h = x @ W_in^T (MFMA, raw x w/ runtime dtype) ----------
__global__ __launch_bounds__(256) void gemm_in(const void* __restrict__ xraw,
                        const int* __restrict__ flags,
                        const unsigned short* __restrict__ Bin,
                        unsigned short* __restrict__ hout, int N)
{
    const int w = threadIdx.x >> 6, lane = threadIdx.x & 63;
    const int m = lane & 15, quad = lane >> 4;
    const int rowBase = blockIdx.x * 32;
    const bool abf = flags[0] != 0;
    f32x4 acc[2][2];
#pragma unroll
    for (int rt = 0; rt < 2; ++rt)
#pragma unroll
        for (int ct = 0; ct < 2; ++ct) acc[rt][ct] = (f32x4){0.f, 0.f, 0.f, 0.f};

#pragma unroll
    for (int ks = 0; ks < 2; ++ks) {
        bf16x8 a[2];
#pragma unroll
        for (int rt = 0; rt < 2; ++rt) {
            long row = rowBase + rt * 16 + m;
            if (abf) {
                a[rt] = *(const bf16x8*)(const void*)((const unsigned short*)xraw + row * 64 + ks * 32 + quad * 8);
            } else {
                const float* xp = (const float*)xraw + row * 64 + ks * 32 + quad * 8;
                float4 f0 = *(const float4*)xp;
                float4 f1 = *(const float4*)(xp + 4);
                bf16x8 t;
                t[0] = (short)f2bf(f0.x); t[1] = (short)f2bf(f0.y);
                t[2] = (short)f2bf(f0.z); t[3] = (short)f2bf(f0.w);
                t[4] = (short)f2bf(f1.x); t[5] = (short)f2bf(f1.y);
                t[6] = (short)f2bf(f1.z); t[7] = (short)f2bf(f1.w);
                a[rt] = t;
            }
        }
#pragma unroll
        for (int ct = 0; ct < 2; ++ct) {
            int t = w * 2 + ct;
            bf16x8 b = *(const bf16x8*)(const void*)(Bin + ((t * 2 + ks) * 64 + lane) * 8);
#pragma unroll
            for (int rt = 0; rt < 2; ++rt)
                acc[rt][ct] = __builtin_amdgcn_mfma_f32_16x16x32_bf16(a[rt], b, acc[rt][ct], 0, 0, 0);
        }
    }
#pragma unroll
    for (int rt = 0; rt < 2; ++rt)
#pragma unroll
        for (int ct = 0; ct < 2; ++ct)
#pragma unroll
            for (int reg = 0; reg < 4; ++reg) {
                int row = rowBase + rt * 16 + quad * 4 + reg;
                int col = w * 32 + ct * 16 + m;
                if (row < N) hout[(long)row * 128 + col] = f2bf(acc[rt][ct][reg]);
            }
}

// ---------- MPNN+GRU step: PERSISTENT blocks, B resident (round-8 best) ----------
// Last step (accOut != nullptr) additionally accumulates leaky(h_new) per thread
// (each thread owns a FIXED column) and reduces via 2x shfl_xor + one atomicAdd
// per column per wave -- replaces the entire colsum readout pass (was 68us of
// device-fence + dirty-L2 re-read).
__global__ __launch_bounds__(512, 2) void step_kernel(
    const unsigned short* __restrict__ hin,
    const unsigned short* __restrict__ aggb,
    const unsigned short* __restrict__ Bci,
    const unsigned short* __restrict__ Bhh,
    const float* __restrict__ bip, const float* __restrict__ bhp,
    unsigned short* __restrict__ hout, int N, int ntiles,
    float* __restrict__ accOut)
{
    __shared__ unsigned short lds[16384];  // 2 bufs x (agg[4096] | h[4096]) shorts
    const int tid = threadIdx.x;
    const int w = tid >> 6, lane = tid & 63;
    const int m = lane & 15, quad = lane >> 4;
    const int cg = w >> 1, half = w & 1;
    const int col = cg * 32 + half * 16 + m;
    const int grid = gridDim.x;

    // ---- resident B fragments (loaded once) ----
    bf16x8 bI[4][3], bH[4][3];
#pragma unroll
    for (int ks = 0; ks < 4; ++ks)
#pragma unroll
        for (int g = 0; g < 3; ++g) {
            int t = cg * 6 + g * 2 + half;
            bI[ks][g] = *(const bf16x8*)(const void*)(Bci + (((long)t * 4 + ks) * 64 + lane) * 8);
            bH[ks][g] = *(const bf16x8*)(const void*)(Bhh + (((long)t * 4 + ks) * 64 + lane) * 8);
        }
    // ---- resident biases ----
    float bi0[3], bh0[3];
#pragma unroll
    for (int g = 0; g < 3; ++g) {
        int nc = (cg * 6 + g * 2 + half) * 16 + m;
        bi0[g] = bip[nc]; bh0[g] = bhp[nc];
    }

    // staging geometry (constant per thread)
    const int lrow = w * 4 + (lane >> 4);           // tile row of this lane's 16B
    const int schunk = (lane & 15) ^ (lrow & 7);    // XOR-swizzled source chunk

    float lacc = 0.f;                                // leaky(h_new) column partial

    long tile = blockIdx.x;
    int cur = 0;
    if (tile < ntiles) {
        const unsigned short* gap = aggb + (tile * 32 + lrow) * 128 + schunk * 8;
        const unsigned short* ghp = hin  + (tile * 32 + lrow) * 128 + schunk * 8;
        __builtin_amdgcn_global_load_lds((const ga_u32*)gap, (ls_u32*)(lds + w * 512), 16, 0, 0);
        __builtin_amdgcn_global_load_lds((const ga_u32*)ghp, (ls_u32*)(lds + 4096 + w * 512), 16, 0, 0);
    }

    for (; tile < ntiles; tile += grid) {
        long nxt = tile + grid;
        bool hasNext = nxt < ntiles;
        if (hasNext) {
            int nb = cur ^ 1;
            const unsigned short* gap = aggb + (nxt * 32 + lrow) * 128 + schunk * 8;
            const unsigned short* ghp = hin  + (nxt * 32 + lrow) * 128 + schunk * 8;
            __builtin_amdgcn_global_load_lds((const ga_u32*)gap, (ls_u32*)(lds + nb * 8192 + w * 512), 16, 0, 0);
            __builtin_amdgcn_global_load_lds((const ga_u32*)ghp, (ls_u32*)(lds + nb * 8192 + 4096 + w * 512), 16, 0, 0);
            asm volatile("s_waitcnt vmcnt(2)" ::: "memory");
        } else {
            asm volatile("s_waitcnt vmcnt(0)" ::: "memory");
        }
        __builtin_amdgcn_s_barrier();

        const unsigned short* abuf = lds + cur * 8192;
        const unsigned short* hbuf = lds + cur * 8192 + 4096;

        // accumulators (bias-initialized)
        f32x4 gi[2][3], gh[2][3];
#pragma unroll
        for (int g = 0; g < 3; ++g)
#pragma unroll
            for (int rt = 0; rt < 2; ++rt) {
                gi[rt][g] = (f32x4){bi0[g], bi0[g], bi0[g], bi0[g]};
                gh[rt][g] = (f32x4){bh0[g], bh0[g], bh0[g], bh0[g]};
            }

#pragma unroll
        for (int ks = 0; ks < 4; ++ks) {
            bf16x8 aA[2], hA[2];
#pragma unroll
            for (int rt = 0; rt < 2; ++rt) {
                int r = rt * 16 + m;
                int ch = (ks * 4 + quad) ^ (r & 7);
                aA[rt] = *(const bf16x8*)(const void*)(abuf + r * 128 + ch * 8);
                hA[rt] = *(const bf16x8*)(const void*)(hbuf + r * 128 + ch * 8);
            }
#pragma unroll
            for (int g = 0; g < 3; ++g)
#pragma unroll
                for (int rt = 0; rt < 2; ++rt) {
                    gi[rt][g] = __builtin_amdgcn_mfma_f32_16x16x32_bf16(aA[rt], bI[ks][g], gi[rt][g], 0, 0, 0);
                    gh[rt][g] = __builtin_amdgcn_mfma_f32_16x16x32_bf16(hA[rt], bH[ks][g], gh[rt][g], 0, 0, 0);
                }
        }

        // GRU epilogue: g=0 -> r, g=1 -> z, g=2 -> n; hold re-read from h LDS
        long rowBase = tile * 32;
#pragma unroll
        for (int rt = 0; rt < 2; ++rt)
#pragma unroll
            for (int reg = 0; reg < 4; ++reg) {
                long row = rowBase + rt * 16 + quad * 4 + reg;
                if (row < N) {
                    int r2 = rt * 16 + quad * 4 + reg;
                    int hidx = r2 * 128 + ((((col >> 3) ^ (r2 & 7)) << 3) + (col & 7));
                    float R  = __builtin_amdgcn_rcpf(1.f + __expf(-(gi[rt][0][reg] + gh[rt][0][reg])));
                    float Z  = __builtin_amdgcn_rcpf(1.f + __expf(-(gi[rt][1][reg] + gh[rt][1][reg])));
                    float u  = gi[rt][2][reg] + R * gh[rt][2][reg];
                    float e2 = __expf(-2.f * fabsf(u));
                    float Nn = copysignf((1.f - e2) * __builtin_amdgcn_rcpf(1.f + e2), u);
                    float hold = bf2f(hbuf[hidx]);
                    float hv = (1.f - Z) * Nn + Z * hold;
                    hout[row * 128 + col] = f2bf(hv);
                    lacc += (hv >= 0.f) ? hv : 0.01f * hv;
                }
            }

        __builtin_amdgcn_s_barrier();   // all waves done reading cur before restage
        cur ^= 1;
    }

    // ---- fused readout (last step only): reduce 4 quads sharing this col ----
    if (accOut) {
        lacc += __shfl_xor(lacc, 16);
        lacc += __shfl_xor(lacc, 32);
        if (quad == 0) atomicAdd(&accOut[col], lacc);
    }
}

// ---------- CSR build pass 1: radix partition into coarse buckets ----------
__global__ __launch_bounds__(256) void part1_kernel(
    const int* __restrict__ ei, int E, const int* __restrict__ flags,
    int* __restrict__ gcnt, uint2* __restrict__ pair2,
    int nb, int cshift, int ccap, int chunk)
{
    __shared__ int cnt[256];
    __shared__ int base_s[256];
    const int tid = threadIdx.x;
    if (tid < nb) cnt[tid] = 0;
    __syncthreads();
    const bool i64 = flags[1] != 0;
    const long long* e64 = (const long long*)ei;
    int lo = blockIdx.x * chunk;
    int hi = lo + chunk; if (hi > E) hi = E;
    for (int i = lo + tid; i < hi; i += 256) {
        int d = i64 ? (int)e64[(long)E + i] : ei[(long)E + i];
        atomicAdd(&cnt[d >> cshift], 1);
    }
    __syncthreads();
    if (tid < nb) {
        int c = cnt[tid];
        base_s[tid] = (c > 0) ? atomicAdd(&gcnt[tid], c) : 0;
        cnt[tid] = 0;
    }
    __syncthreads();
    for (int i = lo + tid; i < hi; i += 256) {
        int s, d;
        if (i64) { s = (int)e64[i]; d = (int)e64[(long)E + i]; }
        else     { s = ei[i];       d = ei[(long)E + i]; }
        int c = d >> cshift;
        int p = base_s[c] + atomicAdd(&cnt[c], 1);
        if (p < ccap) { uint2 pr; pr.x = (unsigned)s; pr.y = (unsigned)d; pair2[(long)c * ccap + p] = pr; }
    }
}

// ---------- CSR build pass 2 (scan folded in): counting sort -> offs + csr ----------
__global__ __launch_bounds__(256) void part2_kernel(
    const uint2* __restrict__ pair2, const int* __restrict__ gcnt,
    int* __restrict__ offs, int* __restrict__ csr,
    int N, int nb, int cshift, int ccap)
{
    __shared__ int lb[2048];
    __shared__ int wsum[4];
    __shared__ int cb[257];
    const int b = blockIdx.x, tid = threadIdx.x;
    const int span = 1 << cshift;
    const int n0 = b << cshift;
    int lane = tid & 63, wv = tid >> 6;

    // ---- redundant exclusive scan of clamped gcnt into cb[] ----
    {
        int x = (tid < nb) ? gcnt[tid] : 0;
        if (x > ccap) x = ccap;
        int inc = x;
#pragma unroll
        for (int d = 1; d < 64; d <<= 1) { int u = __shfl_up(inc, d); if (lane >= d) inc += u; }
        if (lane == 63) wsum[wv] = inc;
        __syncthreads();
        if (tid == 0) { int s = 0; for (int q = 0; q < 4; ++q) { int t = wsum[q]; wsum[q] = s; s += t; } }
        __syncthreads();
        int excl = wsum[wv] + inc - x;
        if (tid < nb) cb[tid] = excl;
        if (tid == nb - 1) cb[nb] = excl + x;
    }
    __syncthreads();

    int count = gcnt[b]; if (count > ccap) count = ccap;
    for (int k = tid; k < span; k += 256) lb[k] = 0;
    __syncthreads();
    const uint2* pp = pair2 + (long)b * ccap;
    for (int i = tid; i < count; i += 256)
        atomicAdd(&lb[(int)pp[i].y - n0], 1);
    __syncthreads();
    int npe = span >> 8; if (npe < 1) npe = 1;
    int myb = tid * npe;
    int vals[8];
    int sum = 0;
    for (int k = 0; k < npe; ++k) { vals[k] = lb[myb + k]; sum += vals[k]; }
    int inc = sum;
#pragma unroll
    for (int d = 1; d < 64; d <<= 1) { int u = __shfl_up(inc, d); if (lane >= d) inc += u; }
    if (lane == 63) wsum[wv] = inc;
    __syncthreads();
    if (tid == 0) { int s = 0; for (int q = 0; q < 4; ++q) { int t = wsum[q]; wsum[q] = s; s += t; } }
    __syncthreads();
    int run = wsum[wv] + inc - sum;
    __syncthreads();
    for (int k = 0; k < npe; ++k) { lb[myb + k] = run; run += vals[k]; }
    __syncthreads();
    int gb = cb[b];
    int nn = N - n0; if (nn > span) nn = span;
    for (int g = tid; g < nn; g += 256) offs[n0 + g] = gb + lb[g];
    if (b == nb - 1 && tid == 0) offs[N] = cb[nb];
    __syncthreads();
    for (int i = tid; i < count; i += 256) {
        uint2 pr = pp[i];
        int p = gb + atomicAdd(&lb[(int)pr.y - n0], 1);
        csr[p] = (int)pr.x;
    }
}

// ---------- aggregation: persistent waves, contiguous node chunks ----------
// (pinned at the measured gather ceiling ~3.45 TB/s; do not touch)
__global__ __launch_bounds__(256) void aggregate(const unsigned short* __restrict__ hb,
                          const int* __restrict__ off,
                          const int* __restrict__ csr,
                          unsigned short* __restrict__ aggb, int n)
{
    int wv = threadIdx.x >> 6, lane = threadIdx.x & 63;
    int slot = lane >> 4;
    int c16 = lane & 15;
    int nw = gridDim.x * 4;                 // total waves
    int wid = blockIdx.x * 4 + wv;
    int chunk = (n + nw - 1) / nw;
    int lo = wid * chunk;
    int hi = lo + chunk; if (hi > n) hi = n;

    for (int node = lo; node < hi; ++node) {
        int s0 = off[node], s1 = off[node + 1];
        float a0 = 0.f, a1 = 0.f, a2 = 0.f, a3 = 0.f, a4 = 0.f, a5 = 0.f, a6 = 0.f, a7 = 0.f;
        if (s1 > s0) {
            int last = s1 - 1;
            for (int j = s0 + slot; j < s1; j += 16) {
                uint4 vv[4];
                float wt[4];
#pragma unroll
                for (int t = 0; t < 4; ++t) {
                    int jj = j + 4 * t;
                    int idx = csr[jj <= last ? jj : last];
                    vv[t] = *(const uint4*)(const void*)(hb + (long)idx * 128 + c16 * 8);
                    wt[t] = (jj <= last) ? 1.f : 0.f;
                }
#pragma unroll
                for (int t = 0; t < 4; ++t) {
                    a0 = fmaf(bflo(vv[t].x), wt[t], a0);
                    a1 = fmaf(bfhi(vv[t].x), wt[t], a1);
                    a2 = fmaf(bflo(vv[t].y), wt[t], a2);
                    a3 = fmaf(bfhi(vv[t].y), wt[t], a3);
                    a4 = fmaf(bflo(vv[t].z), wt[t], a4);
                    a5 = fmaf(bfhi(vv[t].z), wt[t], a5);
                    a6 = fmaf(bflo(vv[t].w), wt[t], a6);
                    a7 = fmaf(bfhi(vv[t].w), wt[t], a7);
                }
            }
        }
        a0 += __shfl_xor(a0, 16); a1 += __shfl_xor(a1, 16);
        a2 += __shfl_xor(a2, 16); a3 += __shfl_xor(a3, 16);
        a4 += __shfl_xor(a4, 16); a5 += __shfl_xor(a5, 16);
        a6 += __shfl_xor(a6, 16); a7 += __shfl_xor(a7, 16);
        a0 += __shfl_xor(a0, 32); a1 += __shfl_xor(a1, 32);
        a2 += __shfl_xor(a2, 32); a3 += __shfl_xor(a3, 32);
        a4 += __shfl_xor(a4, 32); a5 += __shfl_xor(a5, 32);
        a6 += __shfl_xor(a6, 32); a7 += __shfl_xor(a7, 32);
        if (slot == 0) {
            uint4 o;
            o.x = ((unsigned int)f2bf(a1) << 16) | f2bf(a0);
            o.y = ((unsigned int)f2bf(a3) << 16) | f2bf(a2);
            o.z = ((unsigned int)f2bf(a5) << 16) | f2bf(a4);
            o.w = ((unsigned int)f2bf(a7) << 16) | f2bf(a6);
            *(uint4*)(void*)(aggb + (long)node * 128 + c16 * 8) = o;
        }
    }
}

// ---------- finalize: g = acc/N dot W_pred + b_pred (1 block) ----------
__global__ void finalize(const float* __restrict__ acc,
                         const float* __restrict__ W_pred_f,
                         const float* __restrict__ b_pred_f,
                         unsigned int* __restrict__ out, float invN)
{
    __shared__ float ws2[2];
    int t = threadIdx.x;  // 128 threads
    float v = acc[t] * invN * W_pred_f[t];
#pragma unroll
    for (int d = 32; d >= 1; d >>= 1) v += __shfl_down(v, d);
    if ((t & 63) == 0) ws2[t >> 6] = v;
    __syncthreads();
    if (t == 0) {
        float r = ws2[0] + ws2[1] + b_pred_f[0];
        unsigned int bf = (unsigned int)f2bf(r);
        out[0] = (bf << 16) | bf;   // dual-dtype store
    }
}

// ---------- host ----------
extern "C" void kernel_launch(void* const* d_in, const int* in_sizes, int n_in,
                              void* d_out, int out_size, void* d_ws, size_t ws_size,
                              hipStream_t stream)
{
    const void* x      = d_in[0];
    const int*  ei     = (const int*)d_in[1];
    const void* W_in   = d_in[2];
    const void* W_mpnn = d_in[3];
    const void* W_ih   = d_in[4];
    const void* W_hh   = d_in[5];
    const void* b_ih   = d_in[6];
    const void* b_hh   = d_in[7];
    const void* W_pred = d_in[8];
    const void* b_pred = d_in[9];

    const int N = in_sizes[0] / 64;              // 100000
    const int E = in_sizes[1] / 2;               // 1600000
    const int STEPS = in_sizes[3] / (128 * 128); // 4

    int cshift = 9;
    while ((((N + (1 << cshift) - 1) >> cshift)) > 256 && cshift < 11) cshift++;
    const int NCO = (N + (1 << cshift) - 1) >> cshift;
    const int ccap = (((E / NCO) * 3 / 2 + 1024) + 255) & ~255;
    const int chunk = (E + 255) / 256;

    size_t woff = 0;
    auto carve = [&](size_t bytes) -> void* {
        void* p = (char*)d_ws + woff;
        woff = (woff + bytes + 255) & ~(size_t)255;
        return p;
    };
    int*   flags = (int*)carve(2 * 4);
    float* Wpf   = (float*)carve(128 * 4);
    float* bpf   = (float*)carve(4);
    unsigned short* Bci = (unsigned short*)carve((size_t)STEPS * 49152 * 2);
    unsigned short* Bhh = (unsigned short*)carve(49152 * 2);
    unsigned short* Bin = (unsigned short*)carve(8192 * 2);
    float* bip   = (float*)carve(384 * 4);
    float* bhp   = (float*)carve(384 * 4);
    unsigned short* hA   = (unsigned short*)carve(((size_t)N * 128 + 16384) * 2);
    unsigned short* hB   = (unsigned short*)carve(((size_t)N * 128 + 16384) * 2);
    unsigned short* aggb = (unsigned short*)carve(((size_t)N * 128 + 16384) * 2);
    int*   offs  = (int*)carve((size_t)(N + 1) * 4);
    int*   csr   = (int*)carve((size_t)E * 4 + 256);
    uint2* pair2 = (uint2*)carve((size_t)NCO * ccap * 8);
    // zero-init region: gcnt | accb (contiguous carves -> ONE memset)
    int*   gcnt  = (int*)carve(256 * 4);
    float* accb  = (float*)carve(128 * 4);
    size_t zbytes = (size_t)((char*)accb - (char*)gcnt) + 256;

    hipMemsetAsync(gcnt, 0, zbytes, stream);

    {
        long total = (long)STEPS * 49152 + 49152 + 768 + 8192 + 128 + 1;
        int blocks = (int)((total + 255) / 256);
        prep_kernel<<<blocks, 256, 0, stream>>>(
            (const unsigned int*)x, ei, W_in, W_mpnn, W_ih, W_hh, b_ih, b_hh,
            W_pred, b_pred, Bci, Bhh, bip, bhp, Bin, Wpf, bpf, flags, STEPS);
    }

    // h0 = x @ W_in^T (reads raw x, runtime dtype)
    gemm_in<<<(N + 31) / 32, 256, 0, stream>>>(x, flags, Bin, hA, N);

    // CSR build: radix partition -> per-bucket counting sort (scan folded in)
    part1_kernel<<<256, 256, 0, stream>>>(ei, E, flags, gcnt, pair2, NCO, cshift, ccap, chunk);
    part2_kernel<<<NCO, 256, 0, stream>>>(pair2, gcnt, offs, csr, N, NCO, cshift, ccap);

    int aggBlocks = (N + 3) / 4; if (aggBlocks > 2048) aggBlocks = 2048;
    const int ntiles = (N + 31) / 32;
    int stepBlocks = ntiles < 256 ? ntiles : 256;
    unsigned short* hcur = hA;
    unsigned short* hnxt = hB;
    for (int step = 0; step < STEPS; ++step) {
        aggregate<<<aggBlocks, 256, 0, stream>>>(hcur, offs, csr, aggb, N);
        step_kernel<<<stepBlocks, 512, 0, stream>>>(
            hcur, aggb, Bci + (size_t)step * 49152, Bhh, bip, bhp, hnxt, N, ntiles,
            (step == STEPS - 1) ? accb : nullptr);
        unsigned short* t = hcur; hcur = hnxt; hnxt = t;
    }

    finalize<<<1, 128, 0, stream>>>(accb, Wpf, bpf, (unsigned int*)d_out, 1.f / (float)N);
}